// Round 2
// 804.565 us; speedup vs baseline: 1.1545x; 1.1545x over previous
//
#include <hip/hip_runtime.h>
#include <cstdint>
#include <cstddef>

#define B_   16
#define D_   192
#define TY   2048
#define TX   512
#define NEG_INF_F (-1e9f)

#define CHUNK 8
#define RING  3
#define WAVES 8

// s_waitcnt imm (gfx9): vmcnt[3:0]=bits3:0, expcnt=bits6:4, lgkmcnt=bits11:8,
// vmcnt[5:4]=bits15:14.
#define WAITVM(N)  __builtin_amdgcn_s_waitcnt(((N) & 15) | (7 << 4) | (15 << 8) | (((N) >> 4) << 14))
#define WAITLGKM0  __builtin_amdgcn_s_waitcnt(15 | (7 << 4) | (0 << 8) | (3 << 14))

__device__ __forceinline__ void gload_lds16(const float* g, float* l) {
    __builtin_amdgcn_global_load_lds(
        (const __attribute__((address_space(1))) void*)g,
        (__attribute__((address_space(3))) void*)l, 16, 0, 0);
}

// lane L <- lane L-1 (lane 0 <- NEG_INF), pure VALU (v_mov_b32_dpp wave_shr:1)
__device__ __forceinline__ float dpp_shr1_neginf(float x) {
    int xi  = __builtin_bit_cast(int, x);
    int old = __builtin_bit_cast(int, NEG_INF_F);
    int r = __builtin_amdgcn_update_dpp(old, xi, 0x138, 0xF, 0xF, false);
    return __builtin_bit_cast(float, r);
}

// ======================= K1: nc14[b,x] = nc1 + nc4 =======================
__global__ __launch_bounds__(256)
void nc14_kernel(const float* __restrict__ m_p,
                 const float* __restrict__ logs_p,
                 float* __restrict__ nc14) {
    int gid = blockIdx.x * 256 + threadIdx.x;       // 0..8191  (B*TX)
    int b = gid >> 9;
    int x = gid & 511;
    const float c = -0.9189385332046727f;           // -0.5*log(2*pi)
    const float* lp = logs_p + (size_t)b * D_ * TX + x;
    const float* mp = m_p    + (size_t)b * D_ * TX + x;
    float acc1 = 0.f, acc2 = 0.f;
    for (int d = 0; d < D_; ++d) {
        float l = lp[(size_t)d * TX];
        float m = mp[(size_t)d * TX];
        float s = __expf(-2.f * l);
        acc1 += c - l;
        acc2 += m * m * s;
    }
    nc14[gid] = acc1 - 0.5f * acc2;
}

// ======================= K2: fp32 GEMM for neg_cent =======================
#define BM 128
#define BN 128
#define BK 16

__global__ __launch_bounds__(512)
void gemm_kernel(const float* __restrict__ z_p,
                 const float* __restrict__ m_p,
                 const float* __restrict__ logs_p,
                 const float* __restrict__ nc14,
                 float* __restrict__ out) {
    __shared__ float a_z [BK][BM];
    __shared__ float a_z2[BK][BM];
    __shared__ float sb_s [BK][BN];
    __shared__ float sb_ms[BK][BN];   // 32 KB total

    const int b  = blockIdx.z;
    const int m0 = blockIdx.y * BM;
    const int n0 = blockIdx.x * BN;
    const int tid = threadIdx.x;
    const int tx = tid & 31;      // 32 col-groups of 4
    const int ty = tid >> 5;      // 16 row-groups of 8

    const int skk = tid >> 5;          // staging row 0..15
    const int sy  = (tid & 31) * 4;    // staging col 0..124

    const float* zb = z_p    + (size_t)b * D_ * TY;
    const float* mb = m_p    + (size_t)b * D_ * TX;
    const float* lb = logs_p + (size_t)b * D_ * TX;

    float acc[8][4];
    #pragma unroll
    for (int i = 0; i < 8; ++i)
        #pragma unroll
        for (int j = 0; j < 4; ++j) acc[i][j] = 0.f;

    float4 va, vlg, vmm;
    auto ld = [&](int k0) {
        va  = *(const float4*)(zb + (size_t)(k0 + skk) * TY + m0 + sy);
        vlg = *(const float4*)(lb + (size_t)(k0 + skk) * TX + n0 + sy);
        vmm = *(const float4*)(mb + (size_t)(k0 + skk) * TX + n0 + sy);
    };
    auto st = [&]() {
        *(float4*)&a_z[skk][sy] = va;
        float4 w;
        w.x = -0.5f * va.x * va.x; w.y = -0.5f * va.y * va.y;
        w.z = -0.5f * va.z * va.z; w.w = -0.5f * va.w * va.w;
        *(float4*)&a_z2[skk][sy] = w;
        float4 s;
        s.x = __expf(-2.f * vlg.x); s.y = __expf(-2.f * vlg.y);
        s.z = __expf(-2.f * vlg.z); s.w = __expf(-2.f * vlg.w);
        *(float4*)&sb_s[skk][sy] = s;
        float4 ms;
        ms.x = vmm.x * s.x; ms.y = vmm.y * s.y;
        ms.z = vmm.z * s.z; ms.w = vmm.w * s.w;
        *(float4*)&sb_ms[skk][sy] = ms;
    };

    ld(0);
    for (int k0 = 0; k0 < D_; k0 += BK) {
        st();
        __syncthreads();
        if (k0 + BK < D_) ld(k0 + BK);   // prefetch next tile during compute
        #pragma unroll
        for (int kk = 0; kk < BK; ++kk) {
            float az[8], a2[8], bs[4], bm[4];
            *(float4*)&az[0] = *(const float4*)&a_z [kk][ty * 8];
            *(float4*)&az[4] = *(const float4*)&a_z [kk][ty * 8 + 4];
            *(float4*)&a2[0] = *(const float4*)&a_z2[kk][ty * 8];
            *(float4*)&a2[4] = *(const float4*)&a_z2[kk][ty * 8 + 4];
            *(float4*)&bs[0] = *(const float4*)&sb_s [kk][tx * 4];
            *(float4*)&bm[0] = *(const float4*)&sb_ms[kk][tx * 4];
            #pragma unroll
            for (int i = 0; i < 8; ++i)
                #pragma unroll
                for (int j = 0; j < 4; ++j)
                    acc[i][j] += a2[i] * bs[j] + az[i] * bm[j];
        }
        __syncthreads();
    }
    const float4 c4 = *(const float4*)(nc14 + b * TX + n0 + tx * 4);
    float* ob = out + (size_t)b * TY * TX + (size_t)m0 * TX + n0 + tx * 4;
    #pragma unroll
    for (int i = 0; i < 8; ++i) {
        float4 r;
        r.x = acc[i][0] + c4.x; r.y = acc[i][1] + c4.y;
        r.z = acc[i][2] + c4.z; r.w = acc[i][3] + c4.w;
        *(float4*)(ob + (size_t)(ty * 8 + i) * TX) = r;
    }
}

// ======================= K3: DP, 8-wave column-split pipeline =======================
// 8 waves per batch, wave w owns columns [64w, 64w+64), 1 element/lane.
// Skewed software pipeline: wave w processes chunk c (8 rows) at iteration c+w.
// Cross-wave boundary (one float/row) passes through a 3-deep LDS ring `bnd`,
// synchronized by one raw s_barrier per iteration (NO __syncthreads -> no
// compiler-inserted vmcnt(0), so global_load_lds prefetch stays in flight).
// Backtrack bits: __ballot gives the wave-packed 64-bit mask for free (SGPR
// uniform), deposited to lane r via cndmask select, one 8B store per chunk per
// wave. Bitmap layout: bit x of row y lives at byte y*64 + (x>>3).
__global__ __launch_bounds__(512, 1)
void dp_kernel(float* __restrict__ out,
               const int* __restrict__ t_xs,
               const int* __restrict__ t_ys,
               int* __restrict__ cumE) {
    const size_t PLANE = (size_t)TY * TX;
    const size_t OFF1  = (size_t)B_ * PLANE;
    const size_t OFF2  = 2 * OFF1;

    __shared__ float rows_lds[WAVES][RING][CHUNK * 64];   // 48 KB
    __shared__ float bnd[RING][WAVES + 1][CHUNK];          // 864 B, [ring][consumer][row]
    __shared__ float dumpf[72];                            // junk sink for non-lane63 bnd writes
    __shared__ int   w_lds[TX];

    const int b    = blockIdx.x;
    const int tid  = threadIdx.x;
    const int w    = tid >> 6;
    const int lane = tid & 63;
    const int t_x  = t_xs[b];
    const int t_y  = t_ys[b];
    const int tym1 = t_y - 1;
    const int NC   = (t_y + CHUNK - 1) / CHUNK;   // t_y >= 1024 -> NC >= 128

    const float* nc   = out + (size_t)b * PLANE;
    float*       attn = out + OFF1 + (size_t)b * PLANE;
    float*       logw = out + OFF2 + (size_t)b * TX;
    unsigned char* bitsb = (unsigned char*)attn;

    w_lds[tid] = 0;
    // wave 0 has no producer: its boundary source is always NEG_INF (never overwritten)
    if (tid < RING * CHUNK) bnd[tid / CHUNK][0][tid % CHUNK] = NEG_INF_F;

    auto issue_chunk = [&](int c) {
        const int slot = c % RING;
        #pragma unroll
        for (int k = 0; k < 2; ++k) {
            int y = c * CHUNK + 4 * k + (lane >> 4);     // 4 rows per 16-lane group
            if (y > tym1) y = tym1;
            const float* gp = nc + (size_t)y * TX + 64 * w + 4 * (lane & 15);
            gload_lds16(gp, &rows_lds[w][slot][k * 256]); // lanes land at +16B*lane
        }
    };

    float cl = NEG_INF_F;
    const bool lane0  = (lane == 0);
    const bool lane63 = (lane == 63);

    issue_chunk(0);
    issue_chunk(1);

    const int ITERS = NC + WAVES - 1;
    for (int i = 0; i < ITERS; ++i) {
        WAITLGKM0;                       // drain own ds ops (incl. bnd writes) pre-barrier
        __asm__ volatile("" ::: "memory");
        __builtin_amdgcn_s_barrier();
        __asm__ volatile("" ::: "memory");
        const int c = i - w;
        if (c < 0 || c >= NC) continue;
        const bool full = (c + 2 < NC);
        if (full) issue_chunk(c + 2);

        const int pc = c % RING;
        // producer's (wave w-1) per-row boundary values for this chunk, written iter i-1;
        // carry = producer's last row of chunk c-1, written iter i-2 (ring slot still live).
        float4 bq0 = *(const float4*)&bnd[pc][w][0];
        float4 bq1 = *(const float4*)&bnd[pc][w][4];
        float carry = bnd[(c + RING - 1) % RING][w][CHUNK - 1];
        float bv[CHUNK] = {carry, bq0.x, bq0.y, bq0.z, bq0.w, bq1.x, bq1.y, bq1.z};

        // vmcnt queue per wave (oldest first), steady: L(c)2 S(c-2)1 L(c+1)2 S(c-1)1 L(c+2)2 = 8
        if (c == 0)      { WAITVM(4); }
        else if (c == 1) { WAITVM(5); }
        else if (full)   { WAITVM(6); }
        else             { WAITVM(0); }
        __asm__ volatile("" ::: "memory");

        const float* vrow = &rows_lds[w][pc][0];
        float vv[CHUNK];
        #pragma unroll
        for (int r = 0; r < CHUNK; ++r) vv[r] = vrow[r * 64 + lane];

        // lane63 publishes its post-update cum for consumer wave w+1; others hit the sink
        float* bwa = lane63 ? &bnd[pc][w + 1][0] : &dumpf[lane];
        const int ybase = c * CHUNK;
        unsigned mlo = 0, mhi = 0;
        #pragma unroll
        for (int r = 0; r < CHUNK; ++r) {
            const int y = ybase + r;
            float sh = dpp_shr1_neginf(cl);
            sh = lane0 ? bv[r] : sh;
            unsigned long long mk = __ballot(cl < sh);     // wave-packed backtrack bits (SGPR)
            float cn = vv[r] + fmaxf(cl, sh);
            if (r == 0 && ybase == 0)                       // DP init row
                cn = (w == 0 && lane0) ? vv[0] : NEG_INF_F;
            if (y < t_y) cl = cn;
            if (lane == r) {                                // deposit row mask into lane r
                mlo = (unsigned)mk;
                mhi = (unsigned)(mk >> 32);
            }
            bwa[r] = cl;
        }
        {
            const int ys = ybase + lane;
            if (lane < CHUNK && ys < t_y)
                *(uint2*)(bitsb + (size_t)ys * 64 + 8 * w) = make_uint2(mlo, mhi);
        }
    }

    // drain all global stores, make every wave's bits visible, then only wave 0 continues
    __builtin_amdgcn_s_waitcnt(0);
    __asm__ volatile("" ::: "memory");
    __builtin_amdgcn_s_barrier();
    __asm__ volatile("" ::: "memory");
    if (w != 0) return;

    // ---------------- backtrack (durations only), prefetched windows ----------------
    int idx  = t_x - 1;
    int yhi  = tym1;
    int ytop = tym1;
    int wh   = idx >> 5;

    unsigned vlo = 0, vhi = 0;
    {
        int cnt0 = (ytop >= 31) ? 32 : (ytop + 1);
        int wlo = (wh > 0) ? wh - 1 : 0;
        if (lane < cnt0) {
            const unsigned* rp = (const unsigned*)(bitsb + (size_t)(ytop - lane) * 64);
            vlo = rp[wlo];
            vhi = rp[wh];
        }
    }
    while (ytop >= 0) {
        const int cnt = (ytop >= 31) ? 32 : (ytop + 1);
        // prefetch next group's 3 candidate words (idx can drop <=32 -> wh' in {wh, wh-1})
        unsigned p0 = 0, p1 = 0, p2 = 0;
        const int ynext = ytop - cnt;
        if (ynext >= 0 && lane < 32) {
            int rr = ynext - lane; if (rr < 0) rr = 0;
            const unsigned* rp = (const unsigned*)(bitsb + (size_t)rr * 64);
            const int w2i = wh;
            const int w1i = (wh > 0) ? wh - 1 : 0;
            const int w0i = (wh > 1) ? wh - 2 : 0;
            p0 = rp[w0i]; p1 = rp[w1i]; p2 = rp[w2i];
        }
        const int base = ((wh > 0) ? wh - 1 : 0) * 32;
        auto body = [&](int i2) {
            int yy = ytop - i2;
            unsigned lo = (unsigned)__builtin_amdgcn_readlane((int)vlo, i2);
            unsigned hi = (unsigned)__builtin_amdgcn_readlane((int)vhi, i2);
            unsigned long long V = ((unsigned long long)hi << 32) | lo;
            int pos   = idx - base;
            int bit   = (int)((V >> pos) & 1ull);
            int force = (idx == yy) ? 1 : 0;
            int move  = (force | bit) & ((idx > 0) ? 1 : 0) & ((yy > 0) ? 1 : 0);
            if (move) {
                if (lane0) w_lds[idx] = yhi - yy + 1;
                yhi = yy - 1;
                idx -= 1;
            }
        };
        if (cnt == 32) {
            #pragma unroll
            for (int i2 = 0; i2 < 32; ++i2) body(i2);
        } else {
            for (int i2 = 0; i2 < cnt; ++i2) body(i2);
        }
        ytop -= cnt;
        if (ytop >= 0) {
            const int whn = idx >> 5;
            vlo = (whn == wh) ? p1 : p0;
            vhi = (whn == wh) ? p2 : p1;
            wh = whn;
        }
    }
    if (lane0) w_lds[idx] = yhi + 1;   // phoneme holding row 0

    // ---------------- logw + prefix-sum -> cumE ----------------
    int v2[8];
    int run = 0;
    #pragma unroll
    for (int j = 0; j < 8; ++j) {
        int wv = w_lds[lane * 8 + j];
        run += wv;
        v2[j] = run;                  // inclusive within lane
    }
    int off = run;
    #pragma unroll
    for (int d = 1; d < 64; d <<= 1) {
        int t = __shfl_up(off, d, 64);
        if (lane >= d) off += t;
    }
    int excl = off - run;             // exclusive across lanes
    #pragma unroll
    for (int j = 0; j < 8; ++j) {
        int x = lane * 8 + j;
        cumE[b * TX + x] = v2[j] + excl;
        int wv = w_lds[x];
        logw[x] = (x < t_x) ? logf((float)wv + 1e-6f) : 0.f;
    }
}

// ======================= K4: attn one-hot fill =======================
__global__ __launch_bounds__(256)
void attn_fill_kernel(const int* __restrict__ cumE,
                      float* __restrict__ out) {
    const size_t PLANE = (size_t)TY * TX;
    const size_t OFF1  = (size_t)B_ * PLANE;
    __shared__ int cs[TX + 1];
    const int b  = blockIdx.y;
    const int y0 = blockIdx.x * 4;
    const int t  = threadIdx.x;
    if (t == 0) cs[0] = 0;
    cs[1 + t]       = cumE[b * TX + t];
    cs[1 + 256 + t] = cumE[b * TX + 256 + t];
    __syncthreads();
    const int y  = y0 + (t >> 6);
    const int x0 = (t & 63) * 8;
    float r[8];
    #pragma unroll
    for (int j = 0; j < 8; ++j)
        r[j] = (cs[x0 + j] <= y && y < cs[x0 + j + 1]) ? 1.f : 0.f;
    float* p = out + OFF1 + (size_t)b * PLANE + (size_t)y * TX + x0;
    *(float4*)p       = *(float4*)&r[0];
    *(float4*)(p + 4) = *(float4*)&r[4];
}

// ======================= launch =======================
extern "C" void kernel_launch(void* const* d_in, const int* in_sizes, int n_in,
                              void* d_out, int out_size, void* d_ws, size_t ws_size,
                              hipStream_t stream) {
    const float* z_p    = (const float*)d_in[0];
    const float* m_p    = (const float*)d_in[1];
    const float* logs_p = (const float*)d_in[2];
    const int* ph_len   = (const int*)d_in[3];
    const int* mel_len  = (const int*)d_in[4];
    float* out  = (float*)d_out;
    float* nc14 = (float*)d_ws;          // 16*512 floats = 32 KB
    int*   cumE = (int*)d_ws;            // reuses nc14's space (dead after gemm)

    nc14_kernel<<<(B_ * TX) / 256, 256, 0, stream>>>(m_p, logs_p, nc14);
    gemm_kernel<<<dim3(TX / BN, TY / BM, B_), 512, 0, stream>>>(z_p, m_p, logs_p, nc14, out);
    dp_kernel<<<B_, WAVES * 64, 0, stream>>>(out, ph_len, mel_len, cumE);
    attn_fill_kernel<<<dim3(TY / 4, B_), 256, 0, stream>>>(cumE, out);
}

// Round 3
// 748.113 us; speedup vs baseline: 1.2417x; 1.0755x over previous
//
#include <hip/hip_runtime.h>
#include <cstdint>
#include <cstddef>

#define B_   16
#define D_   192
#define TY   2048
#define TX   512
#define NEG_INF_F (-1e9f)

#define CHUNK 16
#define RING  4
#define WAVES 8

// s_waitcnt imm (gfx9): vmcnt[3:0]=bits3:0, expcnt=bits6:4, lgkmcnt=bits11:8,
// vmcnt[5:4]=bits15:14.
#define WAITVM(N)  __builtin_amdgcn_s_waitcnt(((N) & 15) | (7 << 4) | (15 << 8) | (((N) >> 4) << 14))
#define WAITLGKM0  __builtin_amdgcn_s_waitcnt(15 | (7 << 4) | (0 << 8) | (3 << 14))

__device__ __forceinline__ void gload_lds16(const float* g, float* l) {
    __builtin_amdgcn_global_load_lds(
        (const __attribute__((address_space(1))) void*)g,
        (__attribute__((address_space(3))) void*)l, 16, 0, 0);
}

// lane L <- lane L-1 (lane 0 <- NEG_INF), pure VALU (v_mov_b32_dpp wave_shr:1)
__device__ __forceinline__ float dpp_shr1_neginf(float x) {
    int xi  = __builtin_bit_cast(int, x);
    int old = __builtin_bit_cast(int, NEG_INF_F);
    int r = __builtin_amdgcn_update_dpp(old, xi, 0x138, 0xF, 0xF, false);
    return __builtin_bit_cast(float, r);
}

// ======================= K1: nc14[b,x] = nc1 + nc4 =======================
__global__ __launch_bounds__(256)
void nc14_kernel(const float* __restrict__ m_p,
                 const float* __restrict__ logs_p,
                 float* __restrict__ nc14) {
    int gid = blockIdx.x * 256 + threadIdx.x;       // 0..8191  (B*TX)
    int b = gid >> 9;
    int x = gid & 511;
    const float c = -0.9189385332046727f;           // -0.5*log(2*pi)
    const float* lp = logs_p + (size_t)b * D_ * TX + x;
    const float* mp = m_p    + (size_t)b * D_ * TX + x;
    float acc1 = 0.f, acc2 = 0.f;
    for (int d = 0; d < D_; ++d) {
        float l = lp[(size_t)d * TX];
        float m = mp[(size_t)d * TX];
        float s = __expf(-2.f * l);
        acc1 += c - l;
        acc2 += m * m * s;
    }
    nc14[gid] = acc1 - 0.5f * acc2;
}

// ======================= K2: fp32 GEMM for neg_cent =======================
#define BM 128
#define BN 128
#define BK 16

__global__ __launch_bounds__(512)
void gemm_kernel(const float* __restrict__ z_p,
                 const float* __restrict__ m_p,
                 const float* __restrict__ logs_p,
                 const float* __restrict__ nc14,
                 float* __restrict__ out) {
    __shared__ float a_z [BK][BM];
    __shared__ float a_z2[BK][BM];
    __shared__ float sb_s [BK][BN];
    __shared__ float sb_ms[BK][BN];   // 32 KB total

    const int b  = blockIdx.z;
    const int m0 = blockIdx.y * BM;
    const int n0 = blockIdx.x * BN;
    const int tid = threadIdx.x;
    const int tx = tid & 31;      // 32 col-groups of 4
    const int ty = tid >> 5;      // 16 row-groups of 8

    const int skk = tid >> 5;          // staging row 0..15
    const int sy  = (tid & 31) * 4;    // staging col 0..124

    const float* zb = z_p    + (size_t)b * D_ * TY;
    const float* mb = m_p    + (size_t)b * D_ * TX;
    const float* lb = logs_p + (size_t)b * D_ * TX;

    float acc[8][4];
    #pragma unroll
    for (int i = 0; i < 8; ++i)
        #pragma unroll
        for (int j = 0; j < 4; ++j) acc[i][j] = 0.f;

    float4 va, vlg, vmm;
    auto ld = [&](int k0) {
        va  = *(const float4*)(zb + (size_t)(k0 + skk) * TY + m0 + sy);
        vlg = *(const float4*)(lb + (size_t)(k0 + skk) * TX + n0 + sy);
        vmm = *(const float4*)(mb + (size_t)(k0 + skk) * TX + n0 + sy);
    };
    auto st = [&]() {
        *(float4*)&a_z[skk][sy] = va;
        float4 w;
        w.x = -0.5f * va.x * va.x; w.y = -0.5f * va.y * va.y;
        w.z = -0.5f * va.z * va.z; w.w = -0.5f * va.w * va.w;
        *(float4*)&a_z2[skk][sy] = w;
        float4 s;
        s.x = __expf(-2.f * vlg.x); s.y = __expf(-2.f * vlg.y);
        s.z = __expf(-2.f * vlg.z); s.w = __expf(-2.f * vlg.w);
        *(float4*)&sb_s[skk][sy] = s;
        float4 ms;
        ms.x = vmm.x * s.x; ms.y = vmm.y * s.y;
        ms.z = vmm.z * s.z; ms.w = vmm.w * s.w;
        *(float4*)&sb_ms[skk][sy] = ms;
    };

    ld(0);
    for (int k0 = 0; k0 < D_; k0 += BK) {
        st();
        __syncthreads();
        if (k0 + BK < D_) ld(k0 + BK);   // prefetch next tile during compute
        #pragma unroll
        for (int kk = 0; kk < BK; ++kk) {
            float az[8], a2[8], bs[4], bm[4];
            *(float4*)&az[0] = *(const float4*)&a_z [kk][ty * 8];
            *(float4*)&az[4] = *(const float4*)&a_z [kk][ty * 8 + 4];
            *(float4*)&a2[0] = *(const float4*)&a_z2[kk][ty * 8];
            *(float4*)&a2[4] = *(const float4*)&a_z2[kk][ty * 8 + 4];
            *(float4*)&bs[0] = *(const float4*)&sb_s [kk][tx * 4];
            *(float4*)&bm[0] = *(const float4*)&sb_ms[kk][tx * 4];
            #pragma unroll
            for (int i = 0; i < 8; ++i)
                #pragma unroll
                for (int j = 0; j < 4; ++j)
                    acc[i][j] += a2[i] * bs[j] + az[i] * bm[j];
        }
        __syncthreads();
    }
    const float4 c4 = *(const float4*)(nc14 + b * TX + n0 + tx * 4);
    float* ob = out + (size_t)b * TY * TX + (size_t)m0 * TX + n0 + tx * 4;
    #pragma unroll
    for (int i = 0; i < 8; ++i) {
        float4 r;
        r.x = acc[i][0] + c4.x; r.y = acc[i][1] + c4.y;
        r.z = acc[i][2] + c4.z; r.w = acc[i][3] + c4.w;
        *(float4*)(ob + (size_t)(ty * 8 + i) * TX) = r;
    }
}

// ======================= K3: DP, 8-wave column-split pipeline =======================
// 8 waves per batch, wave w owns columns [64w, 64w+64), 1 element/lane.
// Skewed software pipeline: wave w processes chunk c (CHUNK=16 rows) at
// iteration c+w. Cross-wave boundary (one float/row) passes through a 4-deep
// LDS ring `bnd`; one raw s_barrier per iteration (no __syncthreads -> no
// compiler vmcnt(0) drain, so global_load_lds prefetch spans barriers).
// Prefetch depth 3 chunks (48 rows) -> load latency decorrelated from barrier.
// Backtrack bits: __ballot packs the wave's 64 compare bits (SGPR), deposited
// to lane r via cndmask; one 8B store per chunk per wave.
__global__ __launch_bounds__(512, 1)
void dp_kernel(float* __restrict__ out,
               const int* __restrict__ t_xs,
               const int* __restrict__ t_ys,
               int* __restrict__ cumE) {
    const size_t PLANE = (size_t)TY * TX;
    const size_t OFF1  = (size_t)B_ * PLANE;
    const size_t OFF2  = 2 * OFF1;

    __shared__ float rows_lds[WAVES][RING][CHUNK * 64];    // 128 KB
    __shared__ float bnd[RING][WAVES + 1][CHUNK];          // 2.25 KB
    __shared__ float dumpf[72];                            // sink for non-lane63 bnd writes
    __shared__ int   w_lds[TX];

    const int b    = blockIdx.x;
    const int tid  = threadIdx.x;
    const int w    = tid >> 6;
    const int lane = tid & 63;
    const int t_x  = t_xs[b];
    const int t_y  = t_ys[b];
    const int tym1 = t_y - 1;
    const int NC   = (t_y + CHUNK - 1) / CHUNK;   // t_y >= 1024 -> NC >= 64

    const float* nc   = out + (size_t)b * PLANE;
    float*       attn = out + OFF1 + (size_t)b * PLANE;
    float*       logw = out + OFF2 + (size_t)b * TX;
    unsigned char* bitsb = (unsigned char*)attn;

    w_lds[tid] = 0;
    // init the whole bnd ring to NEG_INF (wave 0's producer + first-carry slots)
    {
        float* bf = &bnd[0][0][0];                 // RING*(WAVES+1)*CHUNK = 576
        if (tid < 512) bf[tid] = NEG_INF_F;
        if (tid < 64)  bf[512 + tid] = NEG_INF_F;
    }

    auto issue_chunk = [&](int c) {
        const int slot = c % RING;
        #pragma unroll
        for (int k = 0; k < CHUNK / 4; ++k) {
            int y = c * CHUNK + 4 * k + (lane >> 4);     // 4 rows per 16-lane group
            if (y > tym1) y = tym1;
            const float* gp = nc + (size_t)y * TX + 64 * w + 4 * (lane & 15);
            gload_lds16(gp, &rows_lds[w][slot][k * 256]); // lanes land at +16B*lane
        }
    };

    float cl = NEG_INF_F;
    const bool lane0  = (lane == 0);
    const bool lane63 = (lane == 63);

    issue_chunk(0);
    issue_chunk(1);
    issue_chunk(2);

    const int ITERS = NC + WAVES - 1;
    for (int i = 0; i < ITERS; ++i) {
        WAITLGKM0;                       // drain own ds ops (incl. bnd writes) pre-barrier
        __asm__ volatile("" ::: "memory");
        __builtin_amdgcn_s_barrier();
        __asm__ volatile("" ::: "memory");
        const int c = i - w;
        if (c < 0 || c >= NC) continue;
        const bool full = (c + 3 < NC);
        if (full) issue_chunk(c + 3);

        const int pc = c % RING;
        // producer's (wave w-1) per-row boundary values for chunk c (written iter i-1);
        // carry = producer's last row of chunk c-1 (written iter i-2; slot still live).
        float4 bq0 = *(const float4*)&bnd[pc][w][0];
        float4 bq1 = *(const float4*)&bnd[pc][w][4];
        float4 bq2 = *(const float4*)&bnd[pc][w][8];
        float4 bq3 = *(const float4*)&bnd[pc][w][12];
        float carry = bnd[(c + RING - 1) % RING][w][CHUNK - 1];
        float bv[CHUNK] = {carry,
                           bq0.x, bq0.y, bq0.z, bq0.w,
                           bq1.x, bq1.y, bq1.z, bq1.w,
                           bq2.x, bq2.y, bq2.z, bq2.w,
                           bq3.x, bq3.y, bq3.z};

        // vmcnt queue per wave (oldest first), steady state (4 loads/chunk, 1 store):
        // L(c)4 S(c-3)1 L(c+1)4 S(c-2)1 L(c+2)4 S(c-1)1 L(c+3)4 = 19 -> retire L(c): 15
        if (c >= 3) {
            if (full)               { WAITVM(15); }
            else if (c + 3 == NC)   { WAITVM(11); }
            else if (c + 2 == NC)   { WAITVM(7);  }
            else                    { WAITVM(3);  }
        } else {
            if (c == 0)             { WAITVM(12); }
            else if (c == 1)        { WAITVM(13); }
            else                    { WAITVM(14); }
        }
        __asm__ volatile("" ::: "memory");

        const float* vrow = &rows_lds[w][pc][0];
        float vv[CHUNK];
        #pragma unroll
        for (int r = 0; r < CHUNK; ++r) vv[r] = vrow[r * 64 + lane];

        // lane63 publishes its post-update cum for consumer wave w+1; others hit the sink
        float* bwa = lane63 ? &bnd[pc][w + 1][0] : &dumpf[lane];
        const int ybase = c * CHUNK;
        unsigned mlo = 0, mhi = 0;
        #pragma unroll
        for (int r = 0; r < CHUNK; ++r) {
            const int y = ybase + r;
            float sh = dpp_shr1_neginf(cl);
            sh = lane0 ? bv[r] : sh;
            unsigned long long mk = __ballot(cl < sh);     // wave-packed backtrack bits (SGPR)
            float cn = vv[r] + fmaxf(cl, sh);
            if (r == 0 && ybase == 0)                       // DP init row
                cn = (w == 0 && lane0) ? vv[0] : NEG_INF_F;
            if (y < t_y) cl = cn;
            if (lane == r) {                                // deposit row mask into lane r
                mlo = (unsigned)mk;
                mhi = (unsigned)(mk >> 32);
            }
            bwa[r] = cl;
        }
        {
            const int ys = ybase + lane;
            if (lane < CHUNK && ys < t_y)
                *(uint2*)(bitsb + (size_t)ys * 64 + 8 * w) = make_uint2(mlo, mhi);
        }
    }

    // drain all global stores, make every wave's bits visible, then only wave 0 continues
    __builtin_amdgcn_s_waitcnt(0);
    __asm__ volatile("" ::: "memory");
    __builtin_amdgcn_s_barrier();
    __asm__ volatile("" ::: "memory");
    if (w != 0) return;

    // ---------------- backtrack (durations only), prefetched windows ----------------
    int idx  = t_x - 1;
    int yhi  = tym1;
    int ytop = tym1;
    int wh   = idx >> 5;

    unsigned vlo = 0, vhi = 0;
    {
        int cnt0 = (ytop >= 31) ? 32 : (ytop + 1);
        int wlo = (wh > 0) ? wh - 1 : 0;
        if (lane < cnt0) {
            const unsigned* rp = (const unsigned*)(bitsb + (size_t)(ytop - lane) * 64);
            vlo = rp[wlo];
            vhi = rp[wh];
        }
    }
    while (ytop >= 0) {
        const int cnt = (ytop >= 31) ? 32 : (ytop + 1);
        // prefetch next group's 3 candidate words (idx can drop <=32 -> wh' in {wh, wh-1})
        unsigned p0 = 0, p1 = 0, p2 = 0;
        const int ynext = ytop - cnt;
        if (ynext >= 0 && lane < 32) {
            int rr = ynext - lane; if (rr < 0) rr = 0;
            const unsigned* rp = (const unsigned*)(bitsb + (size_t)rr * 64);
            const int w2i = wh;
            const int w1i = (wh > 0) ? wh - 1 : 0;
            const int w0i = (wh > 1) ? wh - 2 : 0;
            p0 = rp[w0i]; p1 = rp[w1i]; p2 = rp[w2i];
        }
        const int base = ((wh > 0) ? wh - 1 : 0) * 32;
        auto body = [&](int i2) {
            int yy = ytop - i2;
            unsigned lo = (unsigned)__builtin_amdgcn_readlane((int)vlo, i2);
            unsigned hi = (unsigned)__builtin_amdgcn_readlane((int)vhi, i2);
            unsigned long long V = ((unsigned long long)hi << 32) | lo;
            int pos   = idx - base;
            int bit   = (int)((V >> pos) & 1ull);
            int force = (idx == yy) ? 1 : 0;
            int move  = (force | bit) & ((idx > 0) ? 1 : 0) & ((yy > 0) ? 1 : 0);
            if (move) {
                if (lane0) w_lds[idx] = yhi - yy + 1;
                yhi = yy - 1;
                idx -= 1;
            }
        };
        if (cnt == 32) {
            #pragma unroll
            for (int i2 = 0; i2 < 32; ++i2) body(i2);
        } else {
            for (int i2 = 0; i2 < cnt; ++i2) body(i2);
        }
        ytop -= cnt;
        if (ytop >= 0) {
            const int whn = idx >> 5;
            vlo = (whn == wh) ? p1 : p0;
            vhi = (whn == wh) ? p2 : p1;
            wh = whn;
        }
    }
    if (lane0) w_lds[idx] = yhi + 1;   // phoneme holding row 0

    // ---------------- logw + prefix-sum -> cumE ----------------
    int v2[8];
    int run = 0;
    #pragma unroll
    for (int j = 0; j < 8; ++j) {
        int wv = w_lds[lane * 8 + j];
        run += wv;
        v2[j] = run;                  // inclusive within lane
    }
    int off = run;
    #pragma unroll
    for (int d = 1; d < 64; d <<= 1) {
        int t = __shfl_up(off, d, 64);
        if (lane >= d) off += t;
    }
    int excl = off - run;             // exclusive across lanes
    #pragma unroll
    for (int j = 0; j < 8; ++j) {
        int x = lane * 8 + j;
        cumE[b * TX + x] = v2[j] + excl;
        int wv = w_lds[x];
        logw[x] = (x < t_x) ? logf((float)wv + 1e-6f) : 0.f;
    }
}

// ======================= K4: attn one-hot fill =======================
__global__ __launch_bounds__(256)
void attn_fill_kernel(const int* __restrict__ cumE,
                      float* __restrict__ out) {
    const size_t PLANE = (size_t)TY * TX;
    const size_t OFF1  = (size_t)B_ * PLANE;
    __shared__ int cs[TX + 1];
    const int b  = blockIdx.y;
    const int y0 = blockIdx.x * 4;
    const int t  = threadIdx.x;
    if (t == 0) cs[0] = 0;
    cs[1 + t]       = cumE[b * TX + t];
    cs[1 + 256 + t] = cumE[b * TX + 256 + t];
    __syncthreads();
    const int y  = y0 + (t >> 6);
    const int x0 = (t & 63) * 8;
    float r[8];
    #pragma unroll
    for (int j = 0; j < 8; ++j)
        r[j] = (cs[x0 + j] <= y && y < cs[x0 + j + 1]) ? 1.f : 0.f;
    float* p = out + OFF1 + (size_t)b * PLANE + (size_t)y * TX + x0;
    *(float4*)p       = *(float4*)&r[0];
    *(float4*)(p + 4) = *(float4*)&r[4];
}

// ======================= launch =======================
extern "C" void kernel_launch(void* const* d_in, const int* in_sizes, int n_in,
                              void* d_out, int out_size, void* d_ws, size_t ws_size,
                              hipStream_t stream) {
    const float* z_p    = (const float*)d_in[0];
    const float* m_p    = (const float*)d_in[1];
    const float* logs_p = (const float*)d_in[2];
    const int* ph_len   = (const int*)d_in[3];
    const int* mel_len  = (const int*)d_in[4];
    float* out  = (float*)d_out;
    float* nc14 = (float*)d_ws;          // 16*512 floats = 32 KB
    int*   cumE = (int*)d_ws;            // reuses nc14's space (dead after gemm)

    nc14_kernel<<<(B_ * TX) / 256, 256, 0, stream>>>(m_p, logs_p, nc14);
    gemm_kernel<<<dim3(TX / BN, TY / BM, B_), 512, 0, stream>>>(z_p, m_p, logs_p, nc14, out);
    dp_kernel<<<B_, WAVES * 64, 0, stream>>>(out, ph_len, mel_len, cumE);
    attn_fill_kernel<<<dim3(TY / 4, B_), 256, 0, stream>>>(cumE, out);
}

// Round 4
// 730.878 us; speedup vs baseline: 1.2709x; 1.0236x over previous
//
#include <hip/hip_runtime.h>
#include <cstdint>
#include <cstddef>

#define B_   16
#define D_   192
#define TY   2048
#define TX   512
#define NEG_INF_F (-1e9f)

#define CHUNK 16
#define RING  4
#define WAVES 8

// s_waitcnt imm (gfx9): vmcnt[3:0]=bits3:0, expcnt=bits6:4, lgkmcnt=bits11:8,
// vmcnt[5:4]=bits15:14.
#define WAITVM(N)  __builtin_amdgcn_s_waitcnt(((N) & 15) | (7 << 4) | (15 << 8) | (((N) >> 4) << 14))
#define WAITLGKM0  __builtin_amdgcn_s_waitcnt(15 | (7 << 4) | (0 << 8) | (3 << 14))

__device__ __forceinline__ void gload_lds16(const float* g, float* l) {
    __builtin_amdgcn_global_load_lds(
        (const __attribute__((address_space(1))) void*)g,
        (__attribute__((address_space(3))) void*)l, 16, 0, 0);
}

// lane L <- lane L-1 (lane 0 <- NEG_INF), pure VALU (v_mov_b32_dpp wave_shr:1)
__device__ __forceinline__ float dpp_shr1_neginf(float x) {
    int xi  = __builtin_bit_cast(int, x);
    int old = __builtin_bit_cast(int, NEG_INF_F);
    int r = __builtin_amdgcn_update_dpp(old, xi, 0x138, 0xF, 0xF, false);
    return __builtin_bit_cast(float, r);
}

// ======================= K1: nc14[b,x] = nc1 + nc4 =======================
__global__ __launch_bounds__(256)
void nc14_kernel(const float* __restrict__ m_p,
                 const float* __restrict__ logs_p,
                 float* __restrict__ nc14) {
    int gid = blockIdx.x * 256 + threadIdx.x;       // 0..8191  (B*TX)
    int b = gid >> 9;
    int x = gid & 511;
    const float c = -0.9189385332046727f;           // -0.5*log(2*pi)
    const float* lp = logs_p + (size_t)b * D_ * TX + x;
    const float* mp = m_p    + (size_t)b * D_ * TX + x;
    float acc1 = 0.f, acc2 = 0.f;
    for (int d = 0; d < D_; ++d) {
        float l = lp[(size_t)d * TX];
        float m = mp[(size_t)d * TX];
        float s = __expf(-2.f * l);
        acc1 += c - l;
        acc2 += m * m * s;
    }
    nc14[gid] = acc1 - 0.5f * acc2;
}

// ======================= K2: fp32 GEMM for neg_cent =======================
#define BM 128
#define BN 128
#define BK 16

__global__ __launch_bounds__(512)
void gemm_kernel(const float* __restrict__ z_p,
                 const float* __restrict__ m_p,
                 const float* __restrict__ logs_p,
                 const float* __restrict__ nc14,
                 float* __restrict__ out) {
    __shared__ float a_z [BK][BM];
    __shared__ float a_z2[BK][BM];
    __shared__ float sb_s [BK][BN];
    __shared__ float sb_ms[BK][BN];   // 32 KB total

    const int b  = blockIdx.z;
    const int m0 = blockIdx.y * BM;
    const int n0 = blockIdx.x * BN;
    const int tid = threadIdx.x;
    const int tx = tid & 31;      // 32 col-groups of 4
    const int ty = tid >> 5;      // 16 row-groups of 8

    const int skk = tid >> 5;          // staging row 0..15
    const int sy  = (tid & 31) * 4;    // staging col 0..124

    const float* zb = z_p    + (size_t)b * D_ * TY;
    const float* mb = m_p    + (size_t)b * D_ * TX;
    const float* lb = logs_p + (size_t)b * D_ * TX;

    float acc[8][4];
    #pragma unroll
    for (int i = 0; i < 8; ++i)
        #pragma unroll
        for (int j = 0; j < 4; ++j) acc[i][j] = 0.f;

    float4 va, vlg, vmm;
    auto ld = [&](int k0) {
        va  = *(const float4*)(zb + (size_t)(k0 + skk) * TY + m0 + sy);
        vlg = *(const float4*)(lb + (size_t)(k0 + skk) * TX + n0 + sy);
        vmm = *(const float4*)(mb + (size_t)(k0 + skk) * TX + n0 + sy);
    };
    auto st = [&]() {
        *(float4*)&a_z[skk][sy] = va;
        float4 w;
        w.x = -0.5f * va.x * va.x; w.y = -0.5f * va.y * va.y;
        w.z = -0.5f * va.z * va.z; w.w = -0.5f * va.w * va.w;
        *(float4*)&a_z2[skk][sy] = w;
        float4 s;
        s.x = __expf(-2.f * vlg.x); s.y = __expf(-2.f * vlg.y);
        s.z = __expf(-2.f * vlg.z); s.w = __expf(-2.f * vlg.w);
        *(float4*)&sb_s[skk][sy] = s;
        float4 ms;
        ms.x = vmm.x * s.x; ms.y = vmm.y * s.y;
        ms.z = vmm.z * s.z; ms.w = vmm.w * s.w;
        *(float4*)&sb_ms[skk][sy] = ms;
    };

    ld(0);
    for (int k0 = 0; k0 < D_; k0 += BK) {
        st();
        __syncthreads();
        if (k0 + BK < D_) ld(k0 + BK);   // prefetch next tile during compute
        #pragma unroll
        for (int kk = 0; kk < BK; ++kk) {
            float az[8], a2[8], bs[4], bm[4];
            *(float4*)&az[0] = *(const float4*)&a_z [kk][ty * 8];
            *(float4*)&az[4] = *(const float4*)&a_z [kk][ty * 8 + 4];
            *(float4*)&a2[0] = *(const float4*)&a_z2[kk][ty * 8];
            *(float4*)&a2[4] = *(const float4*)&a_z2[kk][ty * 8 + 4];
            *(float4*)&bs[0] = *(const float4*)&sb_s [kk][tx * 4];
            *(float4*)&bm[0] = *(const float4*)&sb_ms[kk][tx * 4];
            #pragma unroll
            for (int i = 0; i < 8; ++i)
                #pragma unroll
                for (int j = 0; j < 4; ++j)
                    acc[i][j] += a2[i] * bs[j] + az[i] * bm[j];
        }
        __syncthreads();
    }
    const float4 c4 = *(const float4*)(nc14 + b * TX + n0 + tx * 4);
    float* ob = out + (size_t)b * TY * TX + (size_t)m0 * TX + n0 + tx * 4;
    #pragma unroll
    for (int i = 0; i < 8; ++i) {
        float4 r;
        r.x = acc[i][0] + c4.x; r.y = acc[i][1] + c4.y;
        r.z = acc[i][2] + c4.z; r.w = acc[i][3] + c4.w;
        *(float4*)(ob + (size_t)(ty * 8 + i) * TX) = r;
    }
}

// ======================= K3: DP, 8-wave column-split pipeline =======================
// 8 waves per batch, wave w owns columns [64w, 64w+64), 1 element/lane.
// Skewed pipeline: wave w processes chunk c (16 rows) at iteration c+w.
// This round: the 16-row serial loop is PURE VALU — vv[]/bv[] are pinned into
// VGPRs via asm("+v") before the loop (prevents the compiler sinking ds_reads
// into the chain: round-3 VGPR=88 proved demand-loading, ~300cyc/row), and the
// lane63 boundary publish is batched into 4 float4 LDS writes after the loop
// (removes 16 divergent-address ds_writes + dumpf sink from the chain).
__global__ __launch_bounds__(512, 1)
void dp_kernel(float* __restrict__ out,
               const int* __restrict__ t_xs,
               const int* __restrict__ t_ys,
               int* __restrict__ cumE) {
    const size_t PLANE = (size_t)TY * TX;
    const size_t OFF1  = (size_t)B_ * PLANE;
    const size_t OFF2  = 2 * OFF1;

    __shared__ float rows_lds[WAVES][RING][CHUNK * 64];    // 128 KB
    __shared__ float bnd[RING][WAVES + 1][CHUNK];          // 2.25 KB
    __shared__ int   w_lds[TX];

    const int b    = blockIdx.x;
    const int tid  = threadIdx.x;
    const int w    = tid >> 6;
    const int lane = tid & 63;
    const int t_x  = t_xs[b];
    const int t_y  = t_ys[b];
    const int tym1 = t_y - 1;
    const int NC   = (t_y + CHUNK - 1) / CHUNK;   // t_y >= 1024 -> NC >= 64

    const float* nc   = out + (size_t)b * PLANE;
    float*       attn = out + OFF1 + (size_t)b * PLANE;
    float*       logw = out + OFF2 + (size_t)b * TX;
    unsigned char* bitsb = (unsigned char*)attn;

    w_lds[tid] = 0;
    // init the whole bnd ring to NEG_INF (wave 0's producer + first-carry slots)
    {
        float* bf = &bnd[0][0][0];                 // RING*(WAVES+1)*CHUNK = 576
        if (tid < 512) bf[tid] = NEG_INF_F;
        if (tid < 64)  bf[512 + tid] = NEG_INF_F;
    }

    auto issue_chunk = [&](int c) {
        const int slot = c % RING;
        #pragma unroll
        for (int k = 0; k < CHUNK / 4; ++k) {
            int y = c * CHUNK + 4 * k + (lane >> 4);     // 4 rows per 16-lane group
            if (y > tym1) y = tym1;                      // clamp: finite values, rows >= t_y unused
            const float* gp = nc + (size_t)y * TX + 64 * w + 4 * (lane & 15);
            gload_lds16(gp, &rows_lds[w][slot][k * 256]); // lanes land at +16B*lane
        }
    };

    float cl = NEG_INF_F;
    const bool lane0  = (lane == 0);
    const bool lane63 = (lane == 63);

    issue_chunk(0);
    issue_chunk(1);
    issue_chunk(2);

    const int ITERS = NC + WAVES - 1;
    for (int i = 0; i < ITERS; ++i) {
        WAITLGKM0;                       // drain own ds ops (incl. bnd writes) pre-barrier
        __asm__ volatile("" ::: "memory");
        __builtin_amdgcn_s_barrier();
        __asm__ volatile("" ::: "memory");
        const int c = i - w;
        if (c < 0 || c >= NC) continue;
        const bool full = (c + 3 < NC);
        if (full) issue_chunk(c + 3);

        const int pc = c % RING;
        // producer's (wave w-1) per-row boundary values for chunk c (written iter i-1);
        // carry = producer's last row of chunk c-1 (written iter i-2; slot still live).
        float4 bq0 = *(const float4*)&bnd[pc][w][0];
        float4 bq1 = *(const float4*)&bnd[pc][w][4];
        float4 bq2 = *(const float4*)&bnd[pc][w][8];
        float4 bq3 = *(const float4*)&bnd[pc][w][12];
        float carry = bnd[(c + RING - 1) % RING][w][CHUNK - 1];
        float bv[CHUNK] = {carry,
                           bq0.x, bq0.y, bq0.z, bq0.w,
                           bq1.x, bq1.y, bq1.z, bq1.w,
                           bq2.x, bq2.y, bq2.z, bq2.w,
                           bq3.x, bq3.y, bq3.z};

        // vmcnt queue per wave (oldest first), steady state (4 loads/chunk, 1 store):
        // L(c)4 S(c-3)1 L(c+1)4 S(c-2)1 L(c+2)4 S(c-1)1 L(c+3)4 = 19 -> retire L(c): 15
        if (c >= 3) {
            if (full)               { WAITVM(15); }
            else if (c + 3 == NC)   { WAITVM(11); }
            else if (c + 2 == NC)   { WAITVM(7);  }
            else                    { WAITVM(3);  }
        } else {
            if (c == 0)             { WAITVM(12); }
            else if (c == 1)        { WAITVM(13); }
            else                    { WAITVM(14); }
        }
        __asm__ volatile("" ::: "memory");

        // pin bv in VGPRs (prevents re-load inside the row chain)
        #pragma unroll
        for (int r = 0; r < CHUNK; ++r) __asm__ volatile("" : "+v"(bv[r]));

        const float* vrow = &rows_lds[w][pc][0];
        float vv[CHUNK];
        #pragma unroll
        for (int r = 0; r < CHUNK; ++r) vv[r] = vrow[r * 64 + lane];
        // pin vv: forces all 16 ds_reads issued + waited HERE, before the chain
        #pragma unroll
        for (int r = 0; r < CHUNK; ++r) __asm__ volatile("" : "+v"(vv[r]));

        const int ybase = c * CHUNK;
        float pub[CHUNK];
        unsigned mlo = 0, mhi = 0;
        #pragma unroll
        for (int r = 0; r < CHUNK; ++r) {
            float sh = dpp_shr1_neginf(cl);
            sh = lane0 ? bv[r] : sh;
            unsigned long long mk = __ballot(cl < sh);     // wave-packed backtrack bits (SGPR)
            float cn = vv[r] + fmaxf(cl, sh);
            if (r == 0) {                                   // DP init row override (chunk 0 only)
                float iv = (w == 0 && lane0) ? vv[0] : NEG_INF_F;
                cn = (ybase == 0) ? iv : cn;
            }
            cl = cn;                                        // rows y>=t_y: harmless garbage, never read
            pub[r] = cl;
            unsigned lo32 = (unsigned)mk;
            unsigned hi32 = (unsigned)(mk >> 32);
            bool sel = (lane == r);
            mlo = sel ? lo32 : mlo;
            mhi = sel ? hi32 : mhi;
        }
        if (lane63) {   // batched boundary publish for consumer wave w+1
            *(float4*)&bnd[pc][w + 1][0]  = make_float4(pub[0],  pub[1],  pub[2],  pub[3]);
            *(float4*)&bnd[pc][w + 1][4]  = make_float4(pub[4],  pub[5],  pub[6],  pub[7]);
            *(float4*)&bnd[pc][w + 1][8]  = make_float4(pub[8],  pub[9],  pub[10], pub[11]);
            *(float4*)&bnd[pc][w + 1][12] = make_float4(pub[12], pub[13], pub[14], pub[15]);
        }
        {
            const int ys = ybase + lane;
            if (lane < CHUNK && ys < t_y)
                *(uint2*)(bitsb + (size_t)ys * 64 + 8 * w) = make_uint2(mlo, mhi);
        }
    }

    // drain all global stores, make every wave's bits visible, then only wave 0 continues
    __builtin_amdgcn_s_waitcnt(0);
    __asm__ volatile("" ::: "memory");
    __builtin_amdgcn_s_barrier();
    __asm__ volatile("" ::: "memory");
    if (w != 0) return;

    // ---------------- backtrack (durations only), prefetched windows ----------------
    int idx  = t_x - 1;
    int yhi  = tym1;
    int ytop = tym1;
    int wh   = idx >> 5;

    unsigned vlo = 0, vhi = 0;
    {
        int cnt0 = (ytop >= 31) ? 32 : (ytop + 1);
        int wlo = (wh > 0) ? wh - 1 : 0;
        if (lane < cnt0) {
            const unsigned* rp = (const unsigned*)(bitsb + (size_t)(ytop - lane) * 64);
            vlo = rp[wlo];
            vhi = rp[wh];
        }
    }
    while (ytop >= 0) {
        const int cnt = (ytop >= 31) ? 32 : (ytop + 1);
        // prefetch next group's 3 candidate words (idx can drop <=32 -> wh' in {wh, wh-1})
        unsigned p0 = 0, p1 = 0, p2 = 0;
        const int ynext = ytop - cnt;
        if (ynext >= 0 && lane < 32) {
            int rr = ynext - lane; if (rr < 0) rr = 0;
            const unsigned* rp = (const unsigned*)(bitsb + (size_t)rr * 64);
            const int w2i = wh;
            const int w1i = (wh > 0) ? wh - 1 : 0;
            const int w0i = (wh > 1) ? wh - 2 : 0;
            p0 = rp[w0i]; p1 = rp[w1i]; p2 = rp[w2i];
        }
        const int base = ((wh > 0) ? wh - 1 : 0) * 32;
        auto body = [&](int i2) {
            int yy = ytop - i2;
            unsigned lo = (unsigned)__builtin_amdgcn_readlane((int)vlo, i2);
            unsigned hi = (unsigned)__builtin_amdgcn_readlane((int)vhi, i2);
            unsigned long long V = ((unsigned long long)hi << 32) | lo;
            int pos   = idx - base;
            int bit   = (int)((V >> pos) & 1ull);
            int force = (idx == yy) ? 1 : 0;
            int move  = (force | bit) & ((idx > 0) ? 1 : 0) & ((yy > 0) ? 1 : 0);
            if (move) {
                if (lane0) w_lds[idx] = yhi - yy + 1;
                yhi = yy - 1;
                idx -= 1;
            }
        };
        if (cnt == 32) {
            #pragma unroll
            for (int i2 = 0; i2 < 32; ++i2) body(i2);
        } else {
            for (int i2 = 0; i2 < cnt; ++i2) body(i2);
        }
        ytop -= cnt;
        if (ytop >= 0) {
            const int whn = idx >> 5;
            vlo = (whn == wh) ? p1 : p0;
            vhi = (whn == wh) ? p2 : p1;
            wh = whn;
        }
    }
    if (lane0) w_lds[idx] = yhi + 1;   // phoneme holding row 0

    // ---------------- logw + prefix-sum -> cumE ----------------
    int v2[8];
    int run = 0;
    #pragma unroll
    for (int j = 0; j < 8; ++j) {
        int wv = w_lds[lane * 8 + j];
        run += wv;
        v2[j] = run;                  // inclusive within lane
    }
    int off = run;
    #pragma unroll
    for (int d = 1; d < 64; d <<= 1) {
        int t = __shfl_up(off, d, 64);
        if (lane >= d) off += t;
    }
    int excl = off - run;             // exclusive across lanes
    #pragma unroll
    for (int j = 0; j < 8; ++j) {
        int x = lane * 8 + j;
        cumE[b * TX + x] = v2[j] + excl;
        int wv = w_lds[x];
        logw[x] = (x < t_x) ? logf((float)wv + 1e-6f) : 0.f;
    }
}

// ======================= K4: attn one-hot fill =======================
__global__ __launch_bounds__(256)
void attn_fill_kernel(const int* __restrict__ cumE,
                      float* __restrict__ out) {
    const size_t PLANE = (size_t)TY * TX;
    const size_t OFF1  = (size_t)B_ * PLANE;
    __shared__ int cs[TX + 1];
    const int b  = blockIdx.y;
    const int y0 = blockIdx.x * 4;
    const int t  = threadIdx.x;
    if (t == 0) cs[0] = 0;
    cs[1 + t]       = cumE[b * TX + t];
    cs[1 + 256 + t] = cumE[b * TX + 256 + t];
    __syncthreads();
    const int y  = y0 + (t >> 6);
    const int x0 = (t & 63) * 8;
    float r[8];
    #pragma unroll
    for (int j = 0; j < 8; ++j)
        r[j] = (cs[x0 + j] <= y && y < cs[x0 + j + 1]) ? 1.f : 0.f;
    float* p = out + OFF1 + (size_t)b * PLANE + (size_t)y * TX + x0;
    *(float4*)p       = *(float4*)&r[0];
    *(float4*)(p + 4) = *(float4*)&r[4];
}

// ======================= launch =======================
extern "C" void kernel_launch(void* const* d_in, const int* in_sizes, int n_in,
                              void* d_out, int out_size, void* d_ws, size_t ws_size,
                              hipStream_t stream) {
    const float* z_p    = (const float*)d_in[0];
    const float* m_p    = (const float*)d_in[1];
    const float* logs_p = (const float*)d_in[2];
    const int* ph_len   = (const int*)d_in[3];
    const int* mel_len  = (const int*)d_in[4];
    float* out  = (float*)d_out;
    float* nc14 = (float*)d_ws;          // 16*512 floats = 32 KB
    int*   cumE = (int*)d_ws;            // reuses nc14's space (dead after gemm)

    nc14_kernel<<<(B_ * TX) / 256, 256, 0, stream>>>(m_p, logs_p, nc14);
    gemm_kernel<<<dim3(TX / BN, TY / BM, B_), 512, 0, stream>>>(z_p, m_p, logs_p, nc14, out);
    dp_kernel<<<B_, WAVES * 64, 0, stream>>>(out, ph_len, mel_len, cumE);
    attn_fill_kernel<<<dim3(TY / 4, B_), 256, 0, stream>>>(cumE, out);
}

// Round 5
// 701.796 us; speedup vs baseline: 1.3236x; 1.0414x over previous
//
#include <hip/hip_runtime.h>
#include <cstdint>
#include <cstddef>

#define B_   16
#define D_   192
#define TY   2048
#define TX   512
#define NEG_INF_F (-1e9f)

#define CHUNK 16
#define RING  4
#define WAVES 8

// s_waitcnt imm (gfx9): vmcnt[3:0]=bits3:0, expcnt=bits6:4, lgkmcnt=bits11:8,
// vmcnt[5:4]=bits15:14.
#define WAITVM(N)  __builtin_amdgcn_s_waitcnt(((N) & 15) | (7 << 4) | (15 << 8) | (((N) >> 4) << 14))
#define WAITLGKM0  __builtin_amdgcn_s_waitcnt(15 | (7 << 4) | (0 << 8) | (3 << 14))

__device__ __forceinline__ void gload_lds16(const float* g, float* l) {
    __builtin_amdgcn_global_load_lds(
        (const __attribute__((address_space(1))) void*)g,
        (__attribute__((address_space(3))) void*)l, 16, 0, 0);
}

// lane L <- lane L-1 (lane 0 <- NEG_INF), pure VALU (v_mov_b32_dpp wave_shr:1)
__device__ __forceinline__ float dpp_shr1_neginf(float x) {
    int xi  = __builtin_bit_cast(int, x);
    int old = __builtin_bit_cast(int, NEG_INF_F);
    int r = __builtin_amdgcn_update_dpp(old, xi, 0x138, 0xF, 0xF, false);
    return __builtin_bit_cast(float, r);
}

// ======================= K1: nc14[b,x] = nc1 + nc4 =======================
__global__ __launch_bounds__(256)
void nc14_kernel(const float* __restrict__ m_p,
                 const float* __restrict__ logs_p,
                 float* __restrict__ nc14) {
    int gid = blockIdx.x * 256 + threadIdx.x;       // 0..8191  (B*TX)
    int b = gid >> 9;
    int x = gid & 511;
    const float c = -0.9189385332046727f;           // -0.5*log(2*pi)
    const float* lp = logs_p + (size_t)b * D_ * TX + x;
    const float* mp = m_p    + (size_t)b * D_ * TX + x;
    float acc1 = 0.f, acc2 = 0.f;
    for (int d = 0; d < D_; ++d) {
        float l = lp[(size_t)d * TX];
        float m = mp[(size_t)d * TX];
        float s = __expf(-2.f * l);
        acc1 += c - l;
        acc2 += m * m * s;
    }
    nc14[gid] = acc1 - 0.5f * acc2;
}

// ======================= K2: fp32 GEMM for neg_cent =======================
#define BM 128
#define BN 128
#define BK 16

__global__ __launch_bounds__(512)
void gemm_kernel(const float* __restrict__ z_p,
                 const float* __restrict__ m_p,
                 const float* __restrict__ logs_p,
                 const float* __restrict__ nc14,
                 float* __restrict__ out) {
    __shared__ float a_z [BK][BM];
    __shared__ float a_z2[BK][BM];
    __shared__ float sb_s [BK][BN];
    __shared__ float sb_ms[BK][BN];   // 32 KB total

    const int b  = blockIdx.z;
    const int m0 = blockIdx.y * BM;
    const int n0 = blockIdx.x * BN;
    const int tid = threadIdx.x;
    const int tx = tid & 31;      // 32 col-groups of 4
    const int ty = tid >> 5;      // 16 row-groups of 8

    const int skk = tid >> 5;          // staging row 0..15
    const int sy  = (tid & 31) * 4;    // staging col 0..124

    const float* zb = z_p    + (size_t)b * D_ * TY;
    const float* mb = m_p    + (size_t)b * D_ * TX;
    const float* lb = logs_p + (size_t)b * D_ * TX;

    float acc[8][4];
    #pragma unroll
    for (int i = 0; i < 8; ++i)
        #pragma unroll
        for (int j = 0; j < 4; ++j) acc[i][j] = 0.f;

    float4 va, vlg, vmm;
    auto ld = [&](int k0) {
        va  = *(const float4*)(zb + (size_t)(k0 + skk) * TY + m0 + sy);
        vlg = *(const float4*)(lb + (size_t)(k0 + skk) * TX + n0 + sy);
        vmm = *(const float4*)(mb + (size_t)(k0 + skk) * TX + n0 + sy);
    };
    auto st = [&]() {
        *(float4*)&a_z[skk][sy] = va;
        float4 w;
        w.x = -0.5f * va.x * va.x; w.y = -0.5f * va.y * va.y;
        w.z = -0.5f * va.z * va.z; w.w = -0.5f * va.w * va.w;
        *(float4*)&a_z2[skk][sy] = w;
        float4 s;
        s.x = __expf(-2.f * vlg.x); s.y = __expf(-2.f * vlg.y);
        s.z = __expf(-2.f * vlg.z); s.w = __expf(-2.f * vlg.w);
        *(float4*)&sb_s[skk][sy] = s;
        float4 ms;
        ms.x = vmm.x * s.x; ms.y = vmm.y * s.y;
        ms.z = vmm.z * s.z; ms.w = vmm.w * s.w;
        *(float4*)&sb_ms[skk][sy] = ms;
    };

    ld(0);
    for (int k0 = 0; k0 < D_; k0 += BK) {
        st();
        __syncthreads();
        if (k0 + BK < D_) ld(k0 + BK);   // prefetch next tile during compute
        #pragma unroll
        for (int kk = 0; kk < BK; ++kk) {
            float az[8], a2[8], bs[4], bm[4];
            *(float4*)&az[0] = *(const float4*)&a_z [kk][ty * 8];
            *(float4*)&az[4] = *(const float4*)&a_z [kk][ty * 8 + 4];
            *(float4*)&a2[0] = *(const float4*)&a_z2[kk][ty * 8];
            *(float4*)&a2[4] = *(const float4*)&a_z2[kk][ty * 8 + 4];
            *(float4*)&bs[0] = *(const float4*)&sb_s [kk][tx * 4];
            *(float4*)&bm[0] = *(const float4*)&sb_ms[kk][tx * 4];
            #pragma unroll
            for (int i = 0; i < 8; ++i)
                #pragma unroll
                for (int j = 0; j < 4; ++j)
                    acc[i][j] += a2[i] * bs[j] + az[i] * bm[j];
        }
        __syncthreads();
    }
    const float4 c4 = *(const float4*)(nc14 + b * TX + n0 + tx * 4);
    float* ob = out + (size_t)b * TY * TX + (size_t)m0 * TX + n0 + tx * 4;
    #pragma unroll
    for (int i = 0; i < 8; ++i) {
        float4 r;
        r.x = acc[i][0] + c4.x; r.y = acc[i][1] + c4.y;
        r.z = acc[i][2] + c4.z; r.w = acc[i][3] + c4.w;
        *(float4*)(ob + (size_t)(ty * 8 + i) * TX) = r;
    }
}

// ======================= K3: DP, 8-wave column-split pipeline =======================
// Forward: 8 waves per batch, wave w owns columns [64w,64w+64), skewed pipeline
// (chunk c at iteration c+w), boundary through a 4-deep LDS ring, raw s_barrier
// per iteration, global_load_lds prefetch depth 3.
// Backtrack (this round): branch-free SALU core. Per 32-row group, accumulate
// the move decisions into one SGPR bitmask (readlane + shift + cselect per
// step, NO branches, NO LDS on the serial chain), then emit all durations for
// the group in ONE parallel step: lane k with mask bit k set writes
// w_lds[idx0 - popc(mask below k)] = distance to previous set bit.
__global__ __launch_bounds__(512, 1)
void dp_kernel(float* __restrict__ out,
               const int* __restrict__ t_xs,
               const int* __restrict__ t_ys,
               int* __restrict__ cumE) {
    const size_t PLANE = (size_t)TY * TX;
    const size_t OFF1  = (size_t)B_ * PLANE;
    const size_t OFF2  = 2 * OFF1;

    __shared__ float rows_lds[WAVES][RING][CHUNK * 64];    // 128 KB
    __shared__ float bnd[RING][WAVES + 1][CHUNK];          // 2.25 KB
    __shared__ int   w_lds[TX];

    const int b    = blockIdx.x;
    const int tid  = threadIdx.x;
    const int w    = tid >> 6;
    const int lane = tid & 63;
    const int t_x  = t_xs[b];
    const int t_y  = t_ys[b];
    const int tym1 = t_y - 1;
    const int NC   = (t_y + CHUNK - 1) / CHUNK;   // t_y >= 1024 -> NC >= 64

    const float* nc   = out + (size_t)b * PLANE;
    float*       attn = out + OFF1 + (size_t)b * PLANE;
    float*       logw = out + OFF2 + (size_t)b * TX;
    unsigned char* bitsb = (unsigned char*)attn;

    w_lds[tid] = 0;
    // init the whole bnd ring to NEG_INF (wave 0's producer + first-carry slots)
    {
        float* bf = &bnd[0][0][0];                 // RING*(WAVES+1)*CHUNK = 576
        if (tid < 512) bf[tid] = NEG_INF_F;
        if (tid < 64)  bf[512 + tid] = NEG_INF_F;
    }

    auto issue_chunk = [&](int c) {
        const int slot = c % RING;
        #pragma unroll
        for (int k = 0; k < CHUNK / 4; ++k) {
            int y = c * CHUNK + 4 * k + (lane >> 4);     // 4 rows per 16-lane group
            if (y > tym1) y = tym1;                      // clamp: finite values, rows >= t_y unused
            const float* gp = nc + (size_t)y * TX + 64 * w + 4 * (lane & 15);
            gload_lds16(gp, &rows_lds[w][slot][k * 256]); // lanes land at +16B*lane
        }
    };

    float cl = NEG_INF_F;
    const bool lane0  = (lane == 0);
    const bool lane63 = (lane == 63);

    issue_chunk(0);
    issue_chunk(1);
    issue_chunk(2);

    const int ITERS = NC + WAVES - 1;
    for (int i = 0; i < ITERS; ++i) {
        WAITLGKM0;                       // drain own ds ops (incl. bnd writes) pre-barrier
        __asm__ volatile("" ::: "memory");
        __builtin_amdgcn_s_barrier();
        __asm__ volatile("" ::: "memory");
        const int c = i - w;
        if (c < 0 || c >= NC) continue;
        const bool full = (c + 3 < NC);
        if (full) issue_chunk(c + 3);

        const int pc = c % RING;
        // producer's (wave w-1) per-row boundary values for chunk c (written iter i-1);
        // carry = producer's last row of chunk c-1 (written iter i-2; slot still live).
        float4 bq0 = *(const float4*)&bnd[pc][w][0];
        float4 bq1 = *(const float4*)&bnd[pc][w][4];
        float4 bq2 = *(const float4*)&bnd[pc][w][8];
        float4 bq3 = *(const float4*)&bnd[pc][w][12];
        float carry = bnd[(c + RING - 1) % RING][w][CHUNK - 1];
        float bv[CHUNK] = {carry,
                           bq0.x, bq0.y, bq0.z, bq0.w,
                           bq1.x, bq1.y, bq1.z, bq1.w,
                           bq2.x, bq2.y, bq2.z, bq2.w,
                           bq3.x, bq3.y, bq3.z};

        // vmcnt queue per wave (oldest first), steady state (4 loads/chunk, 1 store):
        // L(c)4 S(c-3)1 L(c+1)4 S(c-2)1 L(c+2)4 S(c-1)1 L(c+3)4 = 19 -> retire L(c): 15
        if (c >= 3) {
            if (full)               { WAITVM(15); }
            else if (c + 3 == NC)   { WAITVM(11); }
            else if (c + 2 == NC)   { WAITVM(7);  }
            else                    { WAITVM(3);  }
        } else {
            if (c == 0)             { WAITVM(12); }
            else if (c == 1)        { WAITVM(13); }
            else                    { WAITVM(14); }
        }
        __asm__ volatile("" ::: "memory");

        // pin bv in VGPRs (prevents re-load inside the row chain)
        #pragma unroll
        for (int r = 0; r < CHUNK; ++r) __asm__ volatile("" : "+v"(bv[r]));

        const float* vrow = &rows_lds[w][pc][0];
        float vv[CHUNK];
        #pragma unroll
        for (int r = 0; r < CHUNK; ++r) vv[r] = vrow[r * 64 + lane];
        // pin vv: forces all 16 ds_reads issued + waited HERE, before the chain
        #pragma unroll
        for (int r = 0; r < CHUNK; ++r) __asm__ volatile("" : "+v"(vv[r]));

        const int ybase = c * CHUNK;
        float pub[CHUNK];
        unsigned mlo = 0, mhi = 0;
        #pragma unroll
        for (int r = 0; r < CHUNK; ++r) {
            float sh = dpp_shr1_neginf(cl);
            sh = lane0 ? bv[r] : sh;
            unsigned long long mk = __ballot(cl < sh);     // wave-packed backtrack bits (SGPR)
            float cn = vv[r] + fmaxf(cl, sh);
            if (r == 0) {                                   // DP init row override (chunk 0 only)
                float iv = (w == 0 && lane0) ? vv[0] : NEG_INF_F;
                cn = (ybase == 0) ? iv : cn;
            }
            cl = cn;                                        // rows y>=t_y: harmless garbage, never read
            pub[r] = cl;
            unsigned lo32 = (unsigned)mk;
            unsigned hi32 = (unsigned)(mk >> 32);
            bool sel = (lane == r);
            mlo = sel ? lo32 : mlo;
            mhi = sel ? hi32 : mhi;
        }
        if (lane63) {   // batched boundary publish for consumer wave w+1
            *(float4*)&bnd[pc][w + 1][0]  = make_float4(pub[0],  pub[1],  pub[2],  pub[3]);
            *(float4*)&bnd[pc][w + 1][4]  = make_float4(pub[4],  pub[5],  pub[6],  pub[7]);
            *(float4*)&bnd[pc][w + 1][8]  = make_float4(pub[8],  pub[9],  pub[10], pub[11]);
            *(float4*)&bnd[pc][w + 1][12] = make_float4(pub[12], pub[13], pub[14], pub[15]);
        }
        {
            const int ys = ybase + lane;
            if (lane < CHUNK && ys < t_y)
                *(uint2*)(bitsb + (size_t)ys * 64 + 8 * w) = make_uint2(mlo, mhi);
        }
    }

    // drain all global stores, make every wave's bits visible, then only wave 0 continues
    __builtin_amdgcn_s_waitcnt(0);
    __asm__ volatile("" ::: "memory");
    __builtin_amdgcn_s_barrier();
    __asm__ volatile("" ::: "memory");
    if (w != 0) return;

    // ---------------- backtrack: branch-free SALU core + parallel group emit ----------------
    int idx  = t_x - 1;
    int yhi  = tym1;
    int ytop = tym1;
    int wh   = idx >> 5;

    unsigned vlo = 0, vhi = 0;
    {
        int cnt0 = (ytop >= 31) ? 32 : (ytop + 1);
        int wlo = (wh > 0) ? wh - 1 : 0;
        if (lane < cnt0) {
            const unsigned* rp = (const unsigned*)(bitsb + (size_t)(ytop - lane) * 64);
            vlo = rp[wlo];
            vhi = rp[wh];
        }
    }
    while (ytop >= 0) {
        const int cnt = (ytop >= 31) ? 32 : (ytop + 1);
        // prefetch next group's 3 candidate words (idx can drop <=32 -> wh' in {wh, wh-1})
        unsigned p0 = 0, p1 = 0, p2 = 0;
        const int ynext = ytop - cnt;
        if (ynext >= 0 && lane < 32) {
            int rr = ynext - lane; if (rr < 0) rr = 0;
            const unsigned* rp = (const unsigned*)(bitsb + (size_t)rr * 64);
            const int w2i = wh;
            const int w1i = (wh > 0) ? wh - 1 : 0;
            const int w0i = (wh > 1) ? wh - 2 : 0;
            p0 = rp[w0i]; p1 = rp[w1i]; p2 = rp[w2i];
        }
        const int base  = ((wh > 0) ? wh - 1 : 0) * 32;
        const int idx0  = idx;
        const int yhi0  = yhi;
        unsigned  mask  = 0;
        // branch-free serial core: ~8 SALU per step, no branches, no LDS
        auto step = [&](int i2) {
            int yy = ytop - i2;
            unsigned lo = (unsigned)__builtin_amdgcn_readlane((int)vlo, i2);
            unsigned hi = (unsigned)__builtin_amdgcn_readlane((int)vhi, i2);
            unsigned long long V = ((unsigned long long)hi << 32) | lo;
            int pos   = idx - base;
            int bit   = (int)((V >> pos) & 1ull);
            int force = (idx == yy) ? 1 : 0;
            int move  = (force | bit) & ((idx > 0) ? 1 : 0) & ((yy > 0) ? 1 : 0);
            mask |= ((unsigned)move) << i2;
            yhi  = move ? (yy - 1) : yhi;
            idx -= move;
        };
        if (cnt == 32) {
            #pragma unroll
            for (int i2 = 0; i2 < 32; ++i2) step(i2);
        } else {
            for (int i2 = 0; i2 < cnt; ++i2) step(i2);
        }
        // parallel emit: lane k (set bit k) writes duration of phoneme idx0 - popc(below)
        {
            const int k = lane;
            if (k < 32 && ((mask >> k) & 1u)) {
                unsigned pri = mask & ((1u << k) - 1u);   // k==0 -> 0
                int m  = __popc(pri);
                int ph = idx0 - m;
                int dur;
                if (pri) { int kp = 31 - __builtin_clz(pri); dur = k - kp; }
                else     { dur = yhi0 - ytop + k + 1; }
                w_lds[ph] = dur;
            }
        }
        ytop -= cnt;
        if (ytop >= 0) {
            const int whn = idx >> 5;
            vlo = (whn == wh) ? p1 : p0;
            vhi = (whn == wh) ? p2 : p1;
            wh = whn;
        }
    }
    if (lane0) w_lds[idx] = yhi + 1;   // phoneme holding row 0

    // ---------------- logw + prefix-sum -> cumE ----------------
    __asm__ volatile("" ::: "memory");
    int v2[8];
    int run = 0;
    #pragma unroll
    for (int j = 0; j < 8; ++j) {
        int wv = w_lds[lane * 8 + j];
        run += wv;
        v2[j] = run;                  // inclusive within lane
    }
    int off = run;
    #pragma unroll
    for (int d = 1; d < 64; d <<= 1) {
        int t = __shfl_up(off, d, 64);
        if (lane >= d) off += t;
    }
    int excl = off - run;             // exclusive across lanes
    #pragma unroll
    for (int j = 0; j < 8; ++j) {
        int x = lane * 8 + j;
        cumE[b * TX + x] = v2[j] + excl;
        int wv = w_lds[x];
        logw[x] = (x < t_x) ? logf((float)wv + 1e-6f) : 0.f;
    }
}

// ======================= K4: attn one-hot fill =======================
__global__ __launch_bounds__(256)
void attn_fill_kernel(const int* __restrict__ cumE,
                      float* __restrict__ out) {
    const size_t PLANE = (size_t)TY * TX;
    const size_t OFF1  = (size_t)B_ * PLANE;
    __shared__ int cs[TX + 1];
    const int b  = blockIdx.y;
    const int y0 = blockIdx.x * 4;
    const int t  = threadIdx.x;
    if (t == 0) cs[0] = 0;
    cs[1 + t]       = cumE[b * TX + t];
    cs[1 + 256 + t] = cumE[b * TX + 256 + t];
    __syncthreads();
    const int y  = y0 + (t >> 6);
    const int x0 = (t & 63) * 8;
    float r[8];
    #pragma unroll
    for (int j = 0; j < 8; ++j)
        r[j] = (cs[x0 + j] <= y && y < cs[x0 + j + 1]) ? 1.f : 0.f;
    float* p = out + OFF1 + (size_t)b * PLANE + (size_t)y * TX + x0;
    *(float4*)p       = *(float4*)&r[0];
    *(float4*)(p + 4) = *(float4*)&r[4];
}

// ======================= launch =======================
extern "C" void kernel_launch(void* const* d_in, const int* in_sizes, int n_in,
                              void* d_out, int out_size, void* d_ws, size_t ws_size,
                              hipStream_t stream) {
    const float* z_p    = (const float*)d_in[0];
    const float* m_p    = (const float*)d_in[1];
    const float* logs_p = (const float*)d_in[2];
    const int* ph_len   = (const int*)d_in[3];
    const int* mel_len  = (const int*)d_in[4];
    float* out  = (float*)d_out;
    float* nc14 = (float*)d_ws;          // 16*512 floats = 32 KB
    int*   cumE = (int*)d_ws;            // reuses nc14's space (dead after gemm)

    nc14_kernel<<<(B_ * TX) / 256, 256, 0, stream>>>(m_p, logs_p, nc14);
    gemm_kernel<<<dim3(TX / BN, TY / BM, B_), 512, 0, stream>>>(z_p, m_p, logs_p, nc14, out);
    dp_kernel<<<B_, WAVES * 64, 0, stream>>>(out, ph_len, mel_len, cumE);
    attn_fill_kernel<<<dim3(TY / 4, B_), 256, 0, stream>>>(cumE, out);
}

// Round 6
// 678.291 us; speedup vs baseline: 1.3695x; 1.0347x over previous
//
#include <hip/hip_runtime.h>
#include <cstdint>
#include <cstddef>

#define B_   16
#define D_   192
#define TY   2048
#define TX   512
#define NEG_INF_F (-1e9f)

#define CHUNK 16
#define RING  4
#define WAVES 8

// s_waitcnt imm (gfx9): vmcnt[3:0]=bits3:0, expcnt=bits6:4, lgkmcnt=bits11:8,
// vmcnt[5:4]=bits15:14.
#define WAITVM(N)  __builtin_amdgcn_s_waitcnt(((N) & 15) | (7 << 4) | (15 << 8) | (((N) >> 4) << 14))
#define WAITLGKM0  __builtin_amdgcn_s_waitcnt(15 | (7 << 4) | (0 << 8) | (3 << 14))

__device__ __forceinline__ void gload_lds16(const float* g, float* l) {
    __builtin_amdgcn_global_load_lds(
        (const __attribute__((address_space(1))) void*)g,
        (__attribute__((address_space(3))) void*)l, 16, 0, 0);
}

// lane L <- lane L-1 (lane 0 <- NEG_INF), pure VALU (v_mov_b32_dpp wave_shr:1)
__device__ __forceinline__ float dpp_shr1_neginf(float x) {
    int xi  = __builtin_bit_cast(int, x);
    int old = __builtin_bit_cast(int, NEG_INF_F);
    int r = __builtin_amdgcn_update_dpp(old, xi, 0x138, 0xF, 0xF, false);
    return __builtin_bit_cast(float, r);
}

// ======================= K1: nc14[b,x] = nc1 + nc4 =======================
__global__ __launch_bounds__(256)
void nc14_kernel(const float* __restrict__ m_p,
                 const float* __restrict__ logs_p,
                 float* __restrict__ nc14) {
    int gid = blockIdx.x * 256 + threadIdx.x;       // 0..8191  (B*TX)
    int b = gid >> 9;
    int x = gid & 511;
    const float c = -0.9189385332046727f;           // -0.5*log(2*pi)
    const float* lp = logs_p + (size_t)b * D_ * TX + x;
    const float* mp = m_p    + (size_t)b * D_ * TX + x;
    float acc1 = 0.f, acc2 = 0.f;
    for (int d = 0; d < D_; ++d) {
        float l = lp[(size_t)d * TX];
        float m = mp[(size_t)d * TX];
        float s = __expf(-2.f * l);
        acc1 += c - l;
        acc2 += m * m * s;
    }
    nc14[gid] = acc1 - 0.5f * acc2;
}

// ======================= K2: fp32 GEMM for neg_cent =======================
#define BM 128
#define BN 128
#define BK 16

__global__ __launch_bounds__(512)
void gemm_kernel(const float* __restrict__ z_p,
                 const float* __restrict__ m_p,
                 const float* __restrict__ logs_p,
                 const float* __restrict__ nc14,
                 float* __restrict__ out) {
    __shared__ float a_z [BK][BM];
    __shared__ float a_z2[BK][BM];
    __shared__ float sb_s [BK][BN];
    __shared__ float sb_ms[BK][BN];   // 32 KB total

    const int b  = blockIdx.z;
    const int m0 = blockIdx.y * BM;
    const int n0 = blockIdx.x * BN;
    const int tid = threadIdx.x;
    const int tx = tid & 31;      // 32 col-groups of 4
    const int ty = tid >> 5;      // 16 row-groups of 8

    const int skk = tid >> 5;          // staging row 0..15
    const int sy  = (tid & 31) * 4;    // staging col 0..124

    const float* zb = z_p    + (size_t)b * D_ * TY;
    const float* mb = m_p    + (size_t)b * D_ * TX;
    const float* lb = logs_p + (size_t)b * D_ * TX;

    float acc[8][4];
    #pragma unroll
    for (int i = 0; i < 8; ++i)
        #pragma unroll
        for (int j = 0; j < 4; ++j) acc[i][j] = 0.f;

    float4 va, vlg, vmm;
    auto ld = [&](int k0) {
        va  = *(const float4*)(zb + (size_t)(k0 + skk) * TY + m0 + sy);
        vlg = *(const float4*)(lb + (size_t)(k0 + skk) * TX + n0 + sy);
        vmm = *(const float4*)(mb + (size_t)(k0 + skk) * TX + n0 + sy);
    };
    auto st = [&]() {
        *(float4*)&a_z[skk][sy] = va;
        float4 w;
        w.x = -0.5f * va.x * va.x; w.y = -0.5f * va.y * va.y;
        w.z = -0.5f * va.z * va.z; w.w = -0.5f * va.w * va.w;
        *(float4*)&a_z2[skk][sy] = w;
        float4 s;
        s.x = __expf(-2.f * vlg.x); s.y = __expf(-2.f * vlg.y);
        s.z = __expf(-2.f * vlg.z); s.w = __expf(-2.f * vlg.w);
        *(float4*)&sb_s[skk][sy] = s;
        float4 ms;
        ms.x = vmm.x * s.x; ms.y = vmm.y * s.y;
        ms.z = vmm.z * s.z; ms.w = vmm.w * s.w;
        *(float4*)&sb_ms[skk][sy] = ms;
    };

    ld(0);
    for (int k0 = 0; k0 < D_; k0 += BK) {
        st();
        __syncthreads();
        if (k0 + BK < D_) ld(k0 + BK);   // prefetch next tile during compute
        #pragma unroll
        for (int kk = 0; kk < BK; ++kk) {
            float az[8], a2[8], bs[4], bm[4];
            *(float4*)&az[0] = *(const float4*)&a_z [kk][ty * 8];
            *(float4*)&az[4] = *(const float4*)&a_z [kk][ty * 8 + 4];
            *(float4*)&a2[0] = *(const float4*)&a_z2[kk][ty * 8];
            *(float4*)&a2[4] = *(const float4*)&a_z2[kk][ty * 8 + 4];
            *(float4*)&bs[0] = *(const float4*)&sb_s [kk][tx * 4];
            *(float4*)&bm[0] = *(const float4*)&sb_ms[kk][tx * 4];
            #pragma unroll
            for (int i = 0; i < 8; ++i)
                #pragma unroll
                for (int j = 0; j < 4; ++j)
                    acc[i][j] += a2[i] * bs[j] + az[i] * bm[j];
        }
        __syncthreads();
    }
    const float4 c4 = *(const float4*)(nc14 + b * TX + n0 + tx * 4);
    float* ob = out + (size_t)b * TY * TX + (size_t)m0 * TX + n0 + tx * 4;
    #pragma unroll
    for (int i = 0; i < 8; ++i) {
        float4 r;
        r.x = acc[i][0] + c4.x; r.y = acc[i][1] + c4.y;
        r.z = acc[i][2] + c4.z; r.w = acc[i][3] + c4.w;
        *(float4*)(ob + (size_t)(ty * 8 + i) * TX) = r;
    }
}

// ======================= K3: DP, 8-wave column-split pipeline =======================
// Forward: 8 waves per batch, wave w owns columns [64w,64w+64), skewed pipeline
// (chunk c at iteration c+w), boundary via 4-deep LDS ring, raw s_barrier/iter.
// THIS ROUND: vv[16]+carry for chunk c+1 are ds_read into REGISTERS at the END
// of iteration i (counted-vmcnt gated), pinned, and complete during the barrier
// wait. Post-barrier critical path = bq read (overlapped by row 0, which needs
// only the prefetched carry) + pure-VALU 16-row chain. Double-buffered register
// sets with explicit parity unroll (no runtime indexing -> no scratch).
__global__ __launch_bounds__(512, 1)
void dp_kernel(float* __restrict__ out,
               const int* __restrict__ t_xs,
               const int* __restrict__ t_ys,
               int* __restrict__ cumE) {
    const size_t PLANE = (size_t)TY * TX;
    const size_t OFF1  = (size_t)B_ * PLANE;
    const size_t OFF2  = 2 * OFF1;

    __shared__ float rows_lds[WAVES][RING][CHUNK * 64];    // 128 KB
    __shared__ float bnd[RING][WAVES + 1][CHUNK];          // 2.25 KB
    __shared__ int   w_lds[TX];

    const int b    = blockIdx.x;
    const int tid  = threadIdx.x;
    const int w    = tid >> 6;
    const int lane = tid & 63;
    const int t_x  = t_xs[b];
    const int t_y  = t_ys[b];
    const int tym1 = t_y - 1;
    const int NC   = (t_y + CHUNK - 1) / CHUNK;   // t_y >= 1024 -> NC >= 64

    const float* nc   = out + (size_t)b * PLANE;
    float*       attn = out + OFF1 + (size_t)b * PLANE;
    float*       logw = out + OFF2 + (size_t)b * TX;
    unsigned char* bitsb = (unsigned char*)attn;

    w_lds[tid] = 0;
    // init the whole bnd ring to NEG_INF (wave 0's producer + first-carry slots)
    {
        float* bf = &bnd[0][0][0];                 // RING*(WAVES+1)*CHUNK = 576
        if (tid < 512) bf[tid] = NEG_INF_F;
        if (tid < 64)  bf[512 + tid] = NEG_INF_F;
    }

    auto issue_chunk = [&](int c) {
        const int slot = c % RING;
        #pragma unroll
        for (int k = 0; k < CHUNK / 4; ++k) {
            int y = c * CHUNK + 4 * k + (lane >> 4);     // 4 rows per 16-lane group
            if (y > tym1) y = tym1;                      // clamp: finite values, rows >= t_y unused
            const float* gp = nc + (size_t)y * TX + 64 * w + 4 * (lane & 15);
            gload_lds16(gp, &rows_lds[w][slot][k * 256]); // lanes land at +16B*lane
        }
    };

    float cl = NEG_INF_F;
    const bool lane0  = (lane == 0);
    const bool lane63 = (lane == 63);

    issue_chunk(0);
    issue_chunk(1);
    issue_chunk(2);

    float vvA[CHUNK], vvB[CHUNK];
    float carryA = NEG_INF_F, carryB = NEG_INF_F;
    #pragma unroll
    for (int r = 0; r < CHUNK; ++r) { vvA[r] = 0.f; vvB[r] = 0.f; }

    // wave 0 computes c=0 at i=0: prefetch its vv NOW.
    // queue: L0(4) L1(4) L2(4) = 12; wait L0-retire -> vmcnt(8)
    if (w == 0) {
        WAITVM(8);
        __asm__ volatile("" ::: "memory");
        const float* vn = &rows_lds[0][0][0];
        #pragma unroll
        for (int r = 0; r < CHUNK; ++r) vvA[r] = vn[r * 64 + lane];
        #pragma unroll
        for (int r = 0; r < CHUNK; ++r) __asm__ volatile("" : "+v"(vvA[r]));
    }

    const int ITERS = NC + WAVES - 1;

    auto body = [&](float (&vvc)[CHUNK], float& carryc,
                    float (&vvn)[CHUNK], float& carryn, int i) {
        WAITLGKM0;                       // drain own ds ops (publish + prefetch) pre-barrier
        __asm__ volatile("" ::: "memory");
        __builtin_amdgcn_s_barrier();
        __asm__ volatile("" ::: "memory");
        const int c = i - w;
        if (c >= 0 && c < NC) {
            if (c + 3 < NC) issue_chunk(c + 3);
            const int pc = c % RING;
            // issue producer-boundary reads; row 0 (needs only carryc) overlaps them
            float4 bq0 = *(const float4*)&bnd[pc][w][0];
            float4 bq1 = *(const float4*)&bnd[pc][w][4];
            float4 bq2 = *(const float4*)&bnd[pc][w][8];
            float4 bq3 = *(const float4*)&bnd[pc][w][12];

            const int ybase = c * CHUNK;
            float pub[CHUNK];
            unsigned mlo = 0, mhi = 0;
            // ---- row 0: carry only, no LDS dependency ----
            {
                float sh = dpp_shr1_neginf(cl);
                sh = lane0 ? carryc : sh;
                unsigned long long mk = __ballot(cl < sh);
                float cn = vvc[0] + fmaxf(cl, sh);
                if (ybase == 0)
                    cn = (w == 0 && lane0) ? vvc[0] : NEG_INF_F;
                cl = cn;
                pub[0] = cl;
                bool sel = (lane == 0);
                mlo = sel ? (unsigned)mk : mlo;
                mhi = sel ? (unsigned)(mk >> 32) : mhi;
            }
            // ---- rows 1..15: boundary from bq (compiler waits lgkm before first use) ----
            float bv1[CHUNK - 1] = {bq0.x, bq0.y, bq0.z, bq0.w,
                                    bq1.x, bq1.y, bq1.z, bq1.w,
                                    bq2.x, bq2.y, bq2.z, bq2.w,
                                    bq3.x, bq3.y, bq3.z};
            #pragma unroll
            for (int r = 1; r < CHUNK; ++r) {
                float sh = dpp_shr1_neginf(cl);
                sh = lane0 ? bv1[r - 1] : sh;
                unsigned long long mk = __ballot(cl < sh);
                float cn = vvc[r] + fmaxf(cl, sh);
                cl = cn;                               // rows y>=t_y: harmless garbage, never read
                pub[r] = cl;
                bool sel = (lane == r);
                mlo = sel ? (unsigned)mk : mlo;
                mhi = sel ? (unsigned)(mk >> 32) : mhi;
            }
            if (lane63) {   // batched boundary publish for consumer wave w+1
                *(float4*)&bnd[pc][w + 1][0]  = make_float4(pub[0],  pub[1],  pub[2],  pub[3]);
                *(float4*)&bnd[pc][w + 1][4]  = make_float4(pub[4],  pub[5],  pub[6],  pub[7]);
                *(float4*)&bnd[pc][w + 1][8]  = make_float4(pub[8],  pub[9],  pub[10], pub[11]);
                *(float4*)&bnd[pc][w + 1][12] = make_float4(pub[12], pub[13], pub[14], pub[15]);
            }
            {
                const int ys = ybase + lane;
                if (lane < CHUNK && ys < t_y)
                    *(uint2*)(bitsb + (size_t)ys * 64 + 8 * w) = make_uint2(mlo, mhi);
            }
        }
        // ---- register prefetch of chunk cp = c+1 for next iteration ----
        const int cp = (i - w) + 1;
        if (cp >= 0 && cp < NC) {
            const int cc = cp - 1;
            // wait L(cp)-retire; N = ops after L(cp) in this wave's vm queue:
            // cp==0: L1,L2 -> 8 | cp==1: L2,L3,S0 -> 9 | cp==2: L3,S0,L4,S1 -> 10
            // steady (cc+4<=NC): S(cc-2),L(cc+2),S(cc-1),L(cc+3),S(cc) -> 11
            // cc+3==NC: no L(cc+3) -> 7 | cc+2==NC: no L(cc+2) either -> 3
            if (cp == 0)            { WAITVM(8);  }
            else if (cp == 1)       { WAITVM(9);  }
            else if (cp == 2)       { WAITVM(10); }
            else if (cc + 4 <= NC)  { WAITVM(11); }
            else if (cc + 3 == NC)  { WAITVM(7);  }
            else                    { WAITVM(3);  }
            __asm__ volatile("" ::: "memory");
            const float* vn = &rows_lds[w][cp % RING][0];
            #pragma unroll
            for (int r = 0; r < CHUNK; ++r) vvn[r] = vn[r * 64 + lane];
            carryn = bnd[(cp + RING - 1) % RING][w][CHUNK - 1];
            #pragma unroll
            for (int r = 0; r < CHUNK; ++r) __asm__ volatile("" : "+v"(vvn[r]));
            __asm__ volatile("" : "+v"(carryn));
        }
    };

    {
        int i = 0;
        while (i < ITERS) {
            body(vvA, carryA, vvB, carryB, i); ++i;
            if (i >= ITERS) break;
            body(vvB, carryB, vvA, carryA, i); ++i;
        }
    }

    // drain all global stores, make every wave's bits visible, then only wave 0 continues
    __builtin_amdgcn_s_waitcnt(0);
    __asm__ volatile("" ::: "memory");
    __builtin_amdgcn_s_barrier();
    __asm__ volatile("" ::: "memory");
    if (w != 0) return;

    // ---------------- backtrack: branch-free SALU core + parallel group emit ----------------
    int idx  = t_x - 1;
    int yhi  = tym1;
    int ytop = tym1;
    int wh   = idx >> 5;

    unsigned vlo = 0, vhi = 0;
    {
        int cnt0 = (ytop >= 31) ? 32 : (ytop + 1);
        int wlo = (wh > 0) ? wh - 1 : 0;
        if (lane < cnt0) {
            const unsigned* rp = (const unsigned*)(bitsb + (size_t)(ytop - lane) * 64);
            vlo = rp[wlo];
            vhi = rp[wh];
        }
    }
    while (ytop >= 0) {
        const int cnt = (ytop >= 31) ? 32 : (ytop + 1);
        // prefetch next group's 3 candidate words (idx can drop <=32 -> wh' in {wh, wh-1})
        unsigned p0 = 0, p1 = 0, p2 = 0;
        const int ynext = ytop - cnt;
        if (ynext >= 0 && lane < 32) {
            int rr = ynext - lane; if (rr < 0) rr = 0;
            const unsigned* rp = (const unsigned*)(bitsb + (size_t)rr * 64);
            const int w2i = wh;
            const int w1i = (wh > 0) ? wh - 1 : 0;
            const int w0i = (wh > 1) ? wh - 2 : 0;
            p0 = rp[w0i]; p1 = rp[w1i]; p2 = rp[w2i];
        }
        const int base  = ((wh > 0) ? wh - 1 : 0) * 32;
        const int idx0  = idx;
        const int yhi0  = yhi;
        unsigned  mask  = 0;
        // branch-free serial core: ~8 SALU per step, no branches, no LDS
        auto step = [&](int i2) {
            int yy = ytop - i2;
            unsigned lo = (unsigned)__builtin_amdgcn_readlane((int)vlo, i2);
            unsigned hi = (unsigned)__builtin_amdgcn_readlane((int)vhi, i2);
            unsigned long long V = ((unsigned long long)hi << 32) | lo;
            int pos   = idx - base;
            int bit   = (int)((V >> pos) & 1ull);
            int force = (idx == yy) ? 1 : 0;
            int move  = (force | bit) & ((idx > 0) ? 1 : 0) & ((yy > 0) ? 1 : 0);
            mask |= ((unsigned)move) << i2;
            yhi  = move ? (yy - 1) : yhi;
            idx -= move;
        };
        if (cnt == 32) {
            #pragma unroll
            for (int i2 = 0; i2 < 32; ++i2) step(i2);
        } else {
            for (int i2 = 0; i2 < cnt; ++i2) step(i2);
        }
        // parallel emit: lane k (set bit k) writes duration of phoneme idx0 - popc(below)
        {
            const int k = lane;
            if (k < 32 && ((mask >> k) & 1u)) {
                unsigned pri = mask & ((1u << k) - 1u);   // k==0 -> 0
                int m  = __popc(pri);
                int ph = idx0 - m;
                int dur;
                if (pri) { int kp = 31 - __builtin_clz(pri); dur = k - kp; }
                else     { dur = yhi0 - ytop + k + 1; }
                w_lds[ph] = dur;
            }
        }
        ytop -= cnt;
        if (ytop >= 0) {
            const int whn = idx >> 5;
            vlo = (whn == wh) ? p1 : p0;
            vhi = (whn == wh) ? p2 : p1;
            wh = whn;
        }
    }
    if (lane0) w_lds[idx] = yhi + 1;   // phoneme holding row 0

    // ---------------- logw + prefix-sum -> cumE ----------------
    __asm__ volatile("" ::: "memory");
    int v2[8];
    int run = 0;
    #pragma unroll
    for (int j = 0; j < 8; ++j) {
        int wv = w_lds[lane * 8 + j];
        run += wv;
        v2[j] = run;                  // inclusive within lane
    }
    int off = run;
    #pragma unroll
    for (int d = 1; d < 64; d <<= 1) {
        int t = __shfl_up(off, d, 64);
        if (lane >= d) off += t;
    }
    int excl = off - run;             // exclusive across lanes
    #pragma unroll
    for (int j = 0; j < 8; ++j) {
        int x = lane * 8 + j;
        cumE[b * TX + x] = v2[j] + excl;
        int wv = w_lds[x];
        logw[x] = (x < t_x) ? logf((float)wv + 1e-6f) : 0.f;
    }
}

// ======================= K4: attn one-hot fill =======================
__global__ __launch_bounds__(256)
void attn_fill_kernel(const int* __restrict__ cumE,
                      float* __restrict__ out) {
    const size_t PLANE = (size_t)TY * TX;
    const size_t OFF1  = (size_t)B_ * PLANE;
    __shared__ int cs[TX + 1];
    const int b  = blockIdx.y;
    const int y0 = blockIdx.x * 4;
    const int t  = threadIdx.x;
    if (t == 0) cs[0] = 0;
    cs[1 + t]       = cumE[b * TX + t];
    cs[1 + 256 + t] = cumE[b * TX + 256 + t];
    __syncthreads();
    const int y  = y0 + (t >> 6);
    const int x0 = (t & 63) * 8;
    float r[8];
    #pragma unroll
    for (int j = 0; j < 8; ++j)
        r[j] = (cs[x0 + j] <= y && y < cs[x0 + j + 1]) ? 1.f : 0.f;
    float* p = out + OFF1 + (size_t)b * PLANE + (size_t)y * TX + x0;
    *(float4*)p       = *(float4*)&r[0];
    *(float4*)(p + 4) = *(float4*)&r[4];
}

// ======================= launch =======================
extern "C" void kernel_launch(void* const* d_in, const int* in_sizes, int n_in,
                              void* d_out, int out_size, void* d_ws, size_t ws_size,
                              hipStream_t stream) {
    const float* z_p    = (const float*)d_in[0];
    const float* m_p    = (const float*)d_in[1];
    const float* logs_p = (const float*)d_in[2];
    const int* ph_len   = (const int*)d_in[3];
    const int* mel_len  = (const int*)d_in[4];
    float* out  = (float*)d_out;
    float* nc14 = (float*)d_ws;          // 16*512 floats = 32 KB
    int*   cumE = (int*)d_ws;            // reuses nc14's space (dead after gemm)

    nc14_kernel<<<(B_ * TX) / 256, 256, 0, stream>>>(m_p, logs_p, nc14);
    gemm_kernel<<<dim3(TX / BN, TY / BM, B_), 512, 0, stream>>>(z_p, m_p, logs_p, nc14, out);
    dp_kernel<<<B_, WAVES * 64, 0, stream>>>(out, ph_len, mel_len, cumE);
    attn_fill_kernel<<<dim3(TY / 4, B_), 256, 0, stream>>>(cumE, out);
}

// Round 7
// 620.882 us; speedup vs baseline: 1.4961x; 1.0925x over previous
//
#include <hip/hip_runtime.h>
#include <cstdint>
#include <cstddef>

#define B_   16
#define D_   192
#define TY   2048
#define TX   512
#define NEG_INF_F (-1e9f)

#define CHUNK 16
#define RING  4
#define WAVES 8

// s_waitcnt imm (gfx9): vmcnt[3:0]=bits3:0, expcnt=bits6:4, lgkmcnt=bits11:8,
// vmcnt[5:4]=bits15:14.
#define WAITVM(N)  __builtin_amdgcn_s_waitcnt(((N) & 15) | (7 << 4) | (15 << 8) | (((N) >> 4) << 14))
#define WAITLGKM0  __builtin_amdgcn_s_waitcnt(15 | (7 << 4) | (0 << 8) | (3 << 14))

__device__ __forceinline__ void gload_lds16(const float* g, float* l) {
    __builtin_amdgcn_global_load_lds(
        (const __attribute__((address_space(1))) void*)g,
        (__attribute__((address_space(3))) void*)l, 16, 0, 0);
}

// lane L <- lane L-1 (lane 0 <- NEG_INF), pure VALU (v_mov_b32_dpp wave_shr:1)
__device__ __forceinline__ float dpp_shr1_neginf(float x) {
    int xi  = __builtin_bit_cast(int, x);
    int old = __builtin_bit_cast(int, NEG_INF_F);
    int r = __builtin_amdgcn_update_dpp(old, xi, 0x138, 0xF, 0xF, false);
    return __builtin_bit_cast(float, r);
}

// ======================= K1: nc14[b,x] = nc1 + nc4 =======================
__global__ __launch_bounds__(256)
void nc14_kernel(const float* __restrict__ m_p,
                 const float* __restrict__ logs_p,
                 float* __restrict__ nc14) {
    int gid = blockIdx.x * 256 + threadIdx.x;       // 0..8191  (B*TX)
    int b = gid >> 9;
    int x = gid & 511;
    const float c = -0.9189385332046727f;           // -0.5*log(2*pi)
    const float* lp = logs_p + (size_t)b * D_ * TX + x;
    const float* mp = m_p    + (size_t)b * D_ * TX + x;
    float acc1 = 0.f, acc2 = 0.f;
    for (int d = 0; d < D_; ++d) {
        float l = lp[(size_t)d * TX];
        float m = mp[(size_t)d * TX];
        float s = __expf(-2.f * l);
        acc1 += c - l;
        acc2 += m * m * s;
    }
    nc14[gid] = acc1 - 0.5f * acc2;
}

// ======================= K2: fp32 GEMM for neg_cent =======================
// Round-7 rebalance: LDS-pipe-bound before (6 b128 reads per 32 FMAs per kk;
// 4 SIMDs share 1 LDS pipe -> LDS demand 3x VALU, VALUBusy 53%). Now 8x8
// register tile, 256 threads: per kk 8 b128 reads feed 128 FMAs -> LDS:VALU
// 1:1 per CU. Arithmetic per element bit-identical (same k order/contraction).
#define BM 128
#define BN 128
#define BK 16
#define PADF 4

__global__ __launch_bounds__(256)
void gemm_kernel(const float* __restrict__ z_p,
                 const float* __restrict__ m_p,
                 const float* __restrict__ logs_p,
                 const float* __restrict__ nc14,
                 float* __restrict__ out) {
    __shared__ float a_z [BK][BM + PADF];
    __shared__ float a_z2[BK][BM + PADF];
    __shared__ float sb_s [BK][BN + PADF];
    __shared__ float sb_ms[BK][BN + PADF];   // ~33.8 KB total

    const int b  = blockIdx.z;
    const int m0 = blockIdx.y * BM;
    const int n0 = blockIdx.x * BN;
    const int tid = threadIdx.x;
    const int tx2 = tid & 15;          // 16 col-groups of 8
    const int ty2 = tid >> 4;          // 16 row-groups of 8

    const int skk = tid >> 4;          // staging row 0..15
    const int sy  = (tid & 15) * 8;    // staging col 0..120

    const float* zb = z_p    + (size_t)b * D_ * TY;
    const float* mb = m_p    + (size_t)b * D_ * TX;
    const float* lb = logs_p + (size_t)b * D_ * TX;

    float acc[8][8];
    #pragma unroll
    for (int i = 0; i < 8; ++i)
        #pragma unroll
        for (int j = 0; j < 8; ++j) acc[i][j] = 0.f;

    float4 va0, va1, vl0, vl1, vm0, vm1;
    auto ld = [&](int k0) {
        const float* zr = zb + (size_t)(k0 + skk) * TY + m0 + sy;
        const float* lr = lb + (size_t)(k0 + skk) * TX + n0 + sy;
        const float* mr = mb + (size_t)(k0 + skk) * TX + n0 + sy;
        va0 = *(const float4*)zr;       va1 = *(const float4*)(zr + 4);
        vl0 = *(const float4*)lr;       vl1 = *(const float4*)(lr + 4);
        vm0 = *(const float4*)mr;       vm1 = *(const float4*)(mr + 4);
    };
    auto st = [&]() {
        *(float4*)&a_z[skk][sy]     = va0;
        *(float4*)&a_z[skk][sy + 4] = va1;
        float4 w0, w1;
        w0.x = -0.5f * va0.x * va0.x; w0.y = -0.5f * va0.y * va0.y;
        w0.z = -0.5f * va0.z * va0.z; w0.w = -0.5f * va0.w * va0.w;
        w1.x = -0.5f * va1.x * va1.x; w1.y = -0.5f * va1.y * va1.y;
        w1.z = -0.5f * va1.z * va1.z; w1.w = -0.5f * va1.w * va1.w;
        *(float4*)&a_z2[skk][sy]     = w0;
        *(float4*)&a_z2[skk][sy + 4] = w1;
        float4 s0, s1;
        s0.x = __expf(-2.f * vl0.x); s0.y = __expf(-2.f * vl0.y);
        s0.z = __expf(-2.f * vl0.z); s0.w = __expf(-2.f * vl0.w);
        s1.x = __expf(-2.f * vl1.x); s1.y = __expf(-2.f * vl1.y);
        s1.z = __expf(-2.f * vl1.z); s1.w = __expf(-2.f * vl1.w);
        *(float4*)&sb_s[skk][sy]     = s0;
        *(float4*)&sb_s[skk][sy + 4] = s1;
        float4 q0, q1;
        q0.x = vm0.x * s0.x; q0.y = vm0.y * s0.y;
        q0.z = vm0.z * s0.z; q0.w = vm0.w * s0.w;
        q1.x = vm1.x * s1.x; q1.y = vm1.y * s1.y;
        q1.z = vm1.z * s1.z; q1.w = vm1.w * s1.w;
        *(float4*)&sb_ms[skk][sy]     = q0;
        *(float4*)&sb_ms[skk][sy + 4] = q1;
    };

    ld(0);
    for (int k0 = 0; k0 < D_; k0 += BK) {
        st();
        __syncthreads();
        if (k0 + BK < D_) ld(k0 + BK);   // prefetch next tile during compute
        #pragma unroll 4
        for (int kk = 0; kk < BK; ++kk) {
            float az[8], a2[8], bs[8], bm[8];
            *(float4*)&az[0] = *(const float4*)&a_z [kk][ty2 * 8];
            *(float4*)&az[4] = *(const float4*)&a_z [kk][ty2 * 8 + 4];
            *(float4*)&a2[0] = *(const float4*)&a_z2[kk][ty2 * 8];
            *(float4*)&a2[4] = *(const float4*)&a_z2[kk][ty2 * 8 + 4];
            *(float4*)&bs[0] = *(const float4*)&sb_s [kk][tx2 * 8];
            *(float4*)&bs[4] = *(const float4*)&sb_s [kk][tx2 * 8 + 4];
            *(float4*)&bm[0] = *(const float4*)&sb_ms[kk][tx2 * 8];
            *(float4*)&bm[4] = *(const float4*)&sb_ms[kk][tx2 * 8 + 4];
            #pragma unroll
            for (int i = 0; i < 8; ++i)
                #pragma unroll
                for (int j = 0; j < 8; ++j)
                    acc[i][j] += a2[i] * bs[j] + az[i] * bm[j];
        }
        __syncthreads();
    }
    const float4 c4a = *(const float4*)(nc14 + b * TX + n0 + tx2 * 8);
    const float4 c4b = *(const float4*)(nc14 + b * TX + n0 + tx2 * 8 + 4);
    float* ob = out + (size_t)b * TY * TX + (size_t)m0 * TX + n0 + tx2 * 8;
    #pragma unroll
    for (int i = 0; i < 8; ++i) {
        float4 r0, r1;
        r0.x = acc[i][0] + c4a.x; r0.y = acc[i][1] + c4a.y;
        r0.z = acc[i][2] + c4a.z; r0.w = acc[i][3] + c4a.w;
        r1.x = acc[i][4] + c4b.x; r1.y = acc[i][5] + c4b.y;
        r1.z = acc[i][6] + c4b.z; r1.w = acc[i][7] + c4b.w;
        float* op = ob + (size_t)(ty2 * 8 + i) * TX;
        *(float4*)op       = r0;
        *(float4*)(op + 4) = r1;
    }
}

// ======================= K3: DP, 8-wave column-split pipeline =======================
// Forward: 8 waves per batch, wave w owns columns [64w,64w+64), skewed pipeline
// (chunk c at iteration c+w), boundary via 4-deep LDS ring, raw s_barrier/iter.
// vv[16]+carry for chunk c+1 are ds_read into REGISTERS at the END of iteration
// i (counted-vmcnt gated), pinned, and complete during the barrier wait.
__global__ __launch_bounds__(512, 1)
void dp_kernel(float* __restrict__ out,
               const int* __restrict__ t_xs,
               const int* __restrict__ t_ys,
               int* __restrict__ cumE) {
    const size_t PLANE = (size_t)TY * TX;
    const size_t OFF1  = (size_t)B_ * PLANE;
    const size_t OFF2  = 2 * OFF1;

    __shared__ float rows_lds[WAVES][RING][CHUNK * 64];    // 128 KB
    __shared__ float bnd[RING][WAVES + 1][CHUNK];          // 2.25 KB
    __shared__ int   w_lds[TX];

    const int b    = blockIdx.x;
    const int tid  = threadIdx.x;
    const int w    = tid >> 6;
    const int lane = tid & 63;
    const int t_x  = t_xs[b];
    const int t_y  = t_ys[b];
    const int tym1 = t_y - 1;
    const int NC   = (t_y + CHUNK - 1) / CHUNK;   // t_y >= 1024 -> NC >= 64

    const float* nc   = out + (size_t)b * PLANE;
    float*       attn = out + OFF1 + (size_t)b * PLANE;
    float*       logw = out + OFF2 + (size_t)b * TX;
    unsigned char* bitsb = (unsigned char*)attn;

    w_lds[tid] = 0;
    // init the whole bnd ring to NEG_INF (wave 0's producer + first-carry slots)
    {
        float* bf = &bnd[0][0][0];                 // RING*(WAVES+1)*CHUNK = 576
        if (tid < 512) bf[tid] = NEG_INF_F;
        if (tid < 64)  bf[512 + tid] = NEG_INF_F;
    }

    auto issue_chunk = [&](int c) {
        const int slot = c % RING;
        #pragma unroll
        for (int k = 0; k < CHUNK / 4; ++k) {
            int y = c * CHUNK + 4 * k + (lane >> 4);     // 4 rows per 16-lane group
            if (y > tym1) y = tym1;                      // clamp: finite values, rows >= t_y unused
            const float* gp = nc + (size_t)y * TX + 64 * w + 4 * (lane & 15);
            gload_lds16(gp, &rows_lds[w][slot][k * 256]); // lanes land at +16B*lane
        }
    };

    float cl = NEG_INF_F;
    const bool lane0  = (lane == 0);
    const bool lane63 = (lane == 63);

    issue_chunk(0);
    issue_chunk(1);
    issue_chunk(2);

    float vvA[CHUNK], vvB[CHUNK];
    float carryA = NEG_INF_F, carryB = NEG_INF_F;
    #pragma unroll
    for (int r = 0; r < CHUNK; ++r) { vvA[r] = 0.f; vvB[r] = 0.f; }

    // wave 0 computes c=0 at i=0: prefetch its vv NOW.
    // queue: L0(4) L1(4) L2(4) = 12; wait L0-retire -> vmcnt(8)
    if (w == 0) {
        WAITVM(8);
        __asm__ volatile("" ::: "memory");
        const float* vn = &rows_lds[0][0][0];
        #pragma unroll
        for (int r = 0; r < CHUNK; ++r) vvA[r] = vn[r * 64 + lane];
        #pragma unroll
        for (int r = 0; r < CHUNK; ++r) __asm__ volatile("" : "+v"(vvA[r]));
    }

    const int ITERS = NC + WAVES - 1;

    auto body = [&](float (&vvc)[CHUNK], float& carryc,
                    float (&vvn)[CHUNK], float& carryn, int i) {
        WAITLGKM0;                       // drain own ds ops (publish + prefetch) pre-barrier
        __asm__ volatile("" ::: "memory");
        __builtin_amdgcn_s_barrier();
        __asm__ volatile("" ::: "memory");
        const int c = i - w;
        if (c >= 0 && c < NC) {
            if (c + 3 < NC) issue_chunk(c + 3);
            const int pc = c % RING;
            // issue producer-boundary reads; row 0 (needs only carryc) overlaps them
            float4 bq0 = *(const float4*)&bnd[pc][w][0];
            float4 bq1 = *(const float4*)&bnd[pc][w][4];
            float4 bq2 = *(const float4*)&bnd[pc][w][8];
            float4 bq3 = *(const float4*)&bnd[pc][w][12];

            const int ybase = c * CHUNK;
            float pub[CHUNK];
            unsigned mlo = 0, mhi = 0;
            // ---- row 0: carry only, no LDS dependency ----
            {
                float sh = dpp_shr1_neginf(cl);
                sh = lane0 ? carryc : sh;
                unsigned long long mk = __ballot(cl < sh);
                float cn = vvc[0] + fmaxf(cl, sh);
                if (ybase == 0)
                    cn = (w == 0 && lane0) ? vvc[0] : NEG_INF_F;
                cl = cn;
                pub[0] = cl;
                bool sel = (lane == 0);
                mlo = sel ? (unsigned)mk : mlo;
                mhi = sel ? (unsigned)(mk >> 32) : mhi;
            }
            // ---- rows 1..15: boundary from bq (compiler waits lgkm before first use) ----
            float bv1[CHUNK - 1] = {bq0.x, bq0.y, bq0.z, bq0.w,
                                    bq1.x, bq1.y, bq1.z, bq1.w,
                                    bq2.x, bq2.y, bq2.z, bq2.w,
                                    bq3.x, bq3.y, bq3.z};
            #pragma unroll
            for (int r = 1; r < CHUNK; ++r) {
                float sh = dpp_shr1_neginf(cl);
                sh = lane0 ? bv1[r - 1] : sh;
                unsigned long long mk = __ballot(cl < sh);
                float cn = vvc[r] + fmaxf(cl, sh);
                cl = cn;                               // rows y>=t_y: harmless garbage, never read
                pub[r] = cl;
                bool sel = (lane == r);
                mlo = sel ? (unsigned)mk : mlo;
                mhi = sel ? (unsigned)(mk >> 32) : mhi;
            }
            if (lane63) {   // batched boundary publish for consumer wave w+1
                *(float4*)&bnd[pc][w + 1][0]  = make_float4(pub[0],  pub[1],  pub[2],  pub[3]);
                *(float4*)&bnd[pc][w + 1][4]  = make_float4(pub[4],  pub[5],  pub[6],  pub[7]);
                *(float4*)&bnd[pc][w + 1][8]  = make_float4(pub[8],  pub[9],  pub[10], pub[11]);
                *(float4*)&bnd[pc][w + 1][12] = make_float4(pub[12], pub[13], pub[14], pub[15]);
            }
            {
                const int ys = ybase + lane;
                if (lane < CHUNK && ys < t_y)
                    *(uint2*)(bitsb + (size_t)ys * 64 + 8 * w) = make_uint2(mlo, mhi);
            }
        }
        // ---- register prefetch of chunk cp = c+1 for next iteration ----
        const int cp = (i - w) + 1;
        if (cp >= 0 && cp < NC) {
            const int cc = cp - 1;
            // wait L(cp)-retire; N = ops after L(cp) in this wave's vm queue:
            // cp==0: L1,L2 -> 8 | cp==1: L2,L3,S0 -> 9 | cp==2: L3,S0,L4,S1 -> 10
            // steady (cc+4<=NC): S(cc-2),L(cc+2),S(cc-1),L(cc+3),S(cc) -> 11
            // cc+3==NC: no L(cc+3) -> 7 | cc+2==NC: no L(cc+2) either -> 3
            if (cp == 0)            { WAITVM(8);  }
            else if (cp == 1)       { WAITVM(9);  }
            else if (cp == 2)       { WAITVM(10); }
            else if (cc + 4 <= NC)  { WAITVM(11); }
            else if (cc + 3 == NC)  { WAITVM(7);  }
            else                    { WAITVM(3);  }
            __asm__ volatile("" ::: "memory");
            const float* vn = &rows_lds[w][cp % RING][0];
            #pragma unroll
            for (int r = 0; r < CHUNK; ++r) vvn[r] = vn[r * 64 + lane];
            carryn = bnd[(cp + RING - 1) % RING][w][CHUNK - 1];
            #pragma unroll
            for (int r = 0; r < CHUNK; ++r) __asm__ volatile("" : "+v"(vvn[r]));
            __asm__ volatile("" : "+v"(carryn));
        }
    };

    {
        int i = 0;
        while (i < ITERS) {
            body(vvA, carryA, vvB, carryB, i); ++i;
            if (i >= ITERS) break;
            body(vvB, carryB, vvA, carryA, i); ++i;
        }
    }

    // drain all global stores, make every wave's bits visible, then only wave 0 continues
    __builtin_amdgcn_s_waitcnt(0);
    __asm__ volatile("" ::: "memory");
    __builtin_amdgcn_s_barrier();
    __asm__ volatile("" ::: "memory");
    if (w != 0) return;

    // ---------------- backtrack: branch-free SALU core + parallel group emit ----------------
    int idx  = t_x - 1;
    int yhi  = tym1;
    int ytop = tym1;
    int wh   = idx >> 5;

    unsigned vlo = 0, vhi = 0;
    {
        int cnt0 = (ytop >= 31) ? 32 : (ytop + 1);
        int wlo = (wh > 0) ? wh - 1 : 0;
        if (lane < cnt0) {
            const unsigned* rp = (const unsigned*)(bitsb + (size_t)(ytop - lane) * 64);
            vlo = rp[wlo];
            vhi = rp[wh];
        }
    }
    while (ytop >= 0) {
        const int cnt = (ytop >= 31) ? 32 : (ytop + 1);
        // prefetch next group's 3 candidate words (idx can drop <=32 -> wh' in {wh, wh-1})
        unsigned p0 = 0, p1 = 0, p2 = 0;
        const int ynext = ytop - cnt;
        if (ynext >= 0 && lane < 32) {
            int rr = ynext - lane; if (rr < 0) rr = 0;
            const unsigned* rp = (const unsigned*)(bitsb + (size_t)rr * 64);
            const int w2i = wh;
            const int w1i = (wh > 0) ? wh - 1 : 0;
            const int w0i = (wh > 1) ? wh - 2 : 0;
            p0 = rp[w0i]; p1 = rp[w1i]; p2 = rp[w2i];
        }
        const int base  = ((wh > 0) ? wh - 1 : 0) * 32;
        const int idx0  = idx;
        const int yhi0  = yhi;
        unsigned  mask  = 0;
        // branch-free serial core: ~8 SALU per step, no branches, no LDS
        auto step = [&](int i2) {
            int yy = ytop - i2;
            unsigned lo = (unsigned)__builtin_amdgcn_readlane((int)vlo, i2);
            unsigned hi = (unsigned)__builtin_amdgcn_readlane((int)vhi, i2);
            unsigned long long V = ((unsigned long long)hi << 32) | lo;
            int pos   = idx - base;
            int bit   = (int)((V >> pos) & 1ull);
            int force = (idx == yy) ? 1 : 0;
            int move  = (force | bit) & ((idx > 0) ? 1 : 0) & ((yy > 0) ? 1 : 0);
            mask |= ((unsigned)move) << i2;
            yhi  = move ? (yy - 1) : yhi;
            idx -= move;
        };
        if (cnt == 32) {
            #pragma unroll
            for (int i2 = 0; i2 < 32; ++i2) step(i2);
        } else {
            for (int i2 = 0; i2 < cnt; ++i2) step(i2);
        }
        // parallel emit: lane k (set bit k) writes duration of phoneme idx0 - popc(below)
        {
            const int k = lane;
            if (k < 32 && ((mask >> k) & 1u)) {
                unsigned pri = mask & ((1u << k) - 1u);   // k==0 -> 0
                int m  = __popc(pri);
                int ph = idx0 - m;
                int dur;
                if (pri) { int kp = 31 - __builtin_clz(pri); dur = k - kp; }
                else     { dur = yhi0 - ytop + k + 1; }
                w_lds[ph] = dur;
            }
        }
        ytop -= cnt;
        if (ytop >= 0) {
            const int whn = idx >> 5;
            vlo = (whn == wh) ? p1 : p0;
            vhi = (whn == wh) ? p2 : p1;
            wh = whn;
        }
    }
    if (lane0) w_lds[idx] = yhi + 1;   // phoneme holding row 0

    // ---------------- logw + prefix-sum -> cumE ----------------
    __asm__ volatile("" ::: "memory");
    int v2[8];
    int run = 0;
    #pragma unroll
    for (int j = 0; j < 8; ++j) {
        int wv = w_lds[lane * 8 + j];
        run += wv;
        v2[j] = run;                  // inclusive within lane
    }
    int off = run;
    #pragma unroll
    for (int d = 1; d < 64; d <<= 1) {
        int t = __shfl_up(off, d, 64);
        if (lane >= d) off += t;
    }
    int excl = off - run;             // exclusive across lanes
    #pragma unroll
    for (int j = 0; j < 8; ++j) {
        int x = lane * 8 + j;
        cumE[b * TX + x] = v2[j] + excl;
        int wv = w_lds[x];
        logw[x] = (x < t_x) ? logf((float)wv + 1e-6f) : 0.f;
    }
}

// ======================= K4: attn one-hot fill =======================
__global__ __launch_bounds__(256)
void attn_fill_kernel(const int* __restrict__ cumE,
                      float* __restrict__ out) {
    const size_t PLANE = (size_t)TY * TX;
    const size_t OFF1  = (size_t)B_ * PLANE;
    __shared__ int cs[TX + 1];
    const int b  = blockIdx.y;
    const int y0 = blockIdx.x * 4;
    const int t  = threadIdx.x;
    if (t == 0) cs[0] = 0;
    cs[1 + t]       = cumE[b * TX + t];
    cs[1 + 256 + t] = cumE[b * TX + 256 + t];
    __syncthreads();
    const int y  = y0 + (t >> 6);
    const int x0 = (t & 63) * 8;
    float r[8];
    #pragma unroll
    for (int j = 0; j < 8; ++j)
        r[j] = (cs[x0 + j] <= y && y < cs[x0 + j + 1]) ? 1.f : 0.f;
    float* p = out + OFF1 + (size_t)b * PLANE + (size_t)y * TX + x0;
    *(float4*)p       = *(float4*)&r[0];
    *(float4*)(p + 4) = *(float4*)&r[4];
}

// ======================= launch =======================
extern "C" void kernel_launch(void* const* d_in, const int* in_sizes, int n_in,
                              void* d_out, int out_size, void* d_ws, size_t ws_size,
                              hipStream_t stream) {
    const float* z_p    = (const float*)d_in[0];
    const float* m_p    = (const float*)d_in[1];
    const float* logs_p = (const float*)d_in[2];
    const int* ph_len   = (const int*)d_in[3];
    const int* mel_len  = (const int*)d_in[4];
    float* out  = (float*)d_out;
    float* nc14 = (float*)d_ws;          // 16*512 floats = 32 KB
    int*   cumE = (int*)d_ws;            // reuses nc14's space (dead after gemm)

    nc14_kernel<<<(B_ * TX) / 256, 256, 0, stream>>>(m_p, logs_p, nc14);
    gemm_kernel<<<dim3(TX / BN, TY / BM, B_), 256, 0, stream>>>(z_p, m_p, logs_p, nc14, out);
    dp_kernel<<<B_, WAVES * 64, 0, stream>>>(out, ph_len, mel_len, cumE);
    attn_fill_kernel<<<dim3(TY / 4, B_), 256, 0, stream>>>(cumE, out);
}